// Round 6
// baseline (97.347 us; speedup 1.0000x reference)
//
#include <hip/hip_runtime.h>
#include <hip/hip_fp16.h>

#define HH 128
#define WW 128
#define HW (HH*WW)
#define XT_BYTES ((size_t)8 * HW * 64 * 2)   // x_t bf16 NHWC
#define WT_BYTES ((size_t)9 * 2 * 4 * 64 * 8 * 2)

typedef __attribute__((ext_vector_type(8))) short short8;
typedef __attribute__((ext_vector_type(4))) float f32x4;

static __device__ __forceinline__ unsigned short f2bf(float f) {
    unsigned int u = __float_as_uint(f);
    u += 0x7fffu + ((u >> 16) & 1u);
    return (unsigned short)(u >> 16);
}
static __device__ __forceinline__ float blo(unsigned int u) {   // low bf16 -> f32
    return __uint_as_float(u << 16);
}
static __device__ __forceinline__ float bhi(unsigned int u) {   // high bf16 -> f32
    return __uint_as_float(u & 0xffff0000u);
}

// weight (64,64,3,3) fp32 -> bf16 B-fragment layout wt[tap][kf][cot][lane][e]
__global__ void wtrans_kernel(const float* __restrict__ w, unsigned short* __restrict__ wt) {
    int i = blockIdx.x * 256 + threadIdx.x;
    if (i < 9 * 2 * 4 * 64 * 8) {
        int e  = i & 7;
        int l  = (i >> 3) & 63;
        int wv = (i >> 9) & 3;
        int kf = (i >> 11) & 1;
        int k  = i >> 12;
        int co = wv * 16 + (l & 15);
        int c  = kf * 32 + (l >> 4) * 8 + e;
        wt[i] = f2bf(w[(co * 64 + c) * 9 + k]);
    }
}

// x [8,64,128,128] f32 -> x_t [8,HW,64] bf16 (NHWC). Block: 64 hw x 64 ch.
__global__ __launch_bounds__(256) void xtrans_kernel(const float* __restrict__ x,
                                                     unsigned int* __restrict__ xt32) {
    __shared__ float tile[64][65];
    const int bid = blockIdx.x;
    const int b   = bid >> 8;
    const int hw0 = (bid & 255) << 6;
    const int t   = threadIdx.x;
    #pragma unroll
    for (int i = 0; i < 16; ++i) {
        int idx = (i << 8) + t;
        int c = idx >> 6, j = idx & 63;
        tile[c][j] = x[(size_t)(((b << 6) + c) << 14) + hw0 + j];
    }
    __syncthreads();
    #pragma unroll
    for (int i = 0; i < 8; ++i) {
        int idx = (i << 8) + t;
        int cp = idx & 31, hw = idx >> 5;
        unsigned u = (unsigned)f2bf(tile[2 * cp][hw]) | ((unsigned)f2bf(tile[2 * cp + 1][hw]) << 16);
        xt32[((size_t)((b << 14) + hw0 + hw) << 5) + cp] = u;
    }
}

// Fast path: block = 64 px (half row), 4 waves; wave w owns px [16w,16w+16) x ALL 64 couts.
// Barrier-free main loop; gathers 2-tap-deep prefetched (3 rotating reg buffers),
// B-fragments 1-deep; sched_barrier(0) pins issue blocks above the combine so the
// compiler cannot sink loads to their use (the round-5 failure mode, VGPR=52).
__global__ __launch_bounds__(256, 2) void deform_nhwc(
    const unsigned short* __restrict__ xt,  // [8][HW][64] bf16
    const float* __restrict__ off,
    const float* __restrict__ msk,
    const unsigned short* __restrict__ wt,  // packed bf16 B-fragments
    const float* __restrict__ bias,
    float* __restrict__ out)
{
    // [0,16384): epilogue transpose tile (unused during main loop)
    // [16384,25600): moS int4 corner byte-offsets [9*64]
    // [25600,30208): mwH packed fp16 bilinear weight pairs [9*64]
    __shared__ __align__(16) unsigned char smem[30208];
    int4*  moS = (int4*)(smem + 16384);
    uint2* mwH = (uint2*)(smem + 25600);

    const int t   = threadIdx.x;
    const int bid = blockIdx.x;
    const int b   = bid & 7;            // image <-> XCD affinity
    const int rem = bid >> 3;
    const int ho  = rem >> 1;
    const int wo0 = (rem & 1) << 6;
    const int l   = t & 63;
    const int wv  = __builtin_amdgcn_readfirstlane(t >> 6);

    // ---- per-(tap,pixel) metadata ----
    for (int i = t; i < 9 * 64; i += 256) {
        int p = i & 63;
        int k = i >> 6;
        int wo = wo0 + p;
        int obase = ((b * 18 + 2 * k) * HH + ho) * WW + wo;
        float oy = off[obase];
        float ox = off[obase + HW];
        float m  = msk[((b * 9 + k) * HH + ho) * WW + wo];
        float py = oy + (float)(k / 3) + (float)(ho - 1);
        float px = ox + (float)(k % 3) + (float)(wo - 1);
        float fy = floorf(py), fx = floorf(px);
        float ly = py - fy,    lx = px - fx;
        int y0 = (int)fy, x0 = (int)fx;
        int y1 = y0 + 1,  x1 = x0 + 1;
        float vy0 = (y0 >= 0 && y0 < HH) ? 1.f : 0.f;
        float vy1 = (y1 >= 0 && y1 < HH) ? 1.f : 0.f;
        float vx0 = (x0 >= 0 && x0 < WW) ? 1.f : 0.f;
        float vx1 = (x1 >= 0 && x1 < WW) ? 1.f : 0.f;
        float w00 = (1.f - ly) * (1.f - lx) * m * vy0 * vx0;
        float w01 = (1.f - ly) * lx         * m * vy0 * vx1;
        float w10 = ly         * (1.f - lx) * m * vy1 * vx0;
        float w11 = ly         * lx         * m * vy1 * vx1;
        int yc0 = min(max(y0, 0), HH - 1), yc1 = min(max(y1, 0), HH - 1);
        int xc0 = min(max(x0, 0), WW - 1), xc1 = min(max(x1, 0), WW - 1);
        moS[i] = make_int4((yc0 * WW + xc0) << 7, (yc0 * WW + xc1) << 7,
                           (yc1 * WW + xc0) << 7, (yc1 * WW + xc1) << 7);
        __half2 hA = __floats2half2_rn(w00, w01);
        __half2 hB = __floats2half2_rn(w10, w11);
        mwH[i] = make_uint2(*(unsigned int*)&hA, *(unsigned int*)&hB);
    }

    const char* ib  = (const char*)xt + (size_t)b * HW * 128;  // image base (bytes)
    const int   px  = (wv << 4) + (l & 15);                    // block-local pixel (A-frag row)
    const int   chb = (l >> 4) << 4;                           // byte offset of 8-ch group

    __syncthreads();   // meta visible

    f32x4 acc[4];
    #pragma unroll
    for (int g = 0; g < 4; ++g) acc[g] = (f32x4){0.f, 0.f, 0.f, 0.f};

    uint4  gg[3][8];   // gather buffers, 2-tap-deep rotation
    short8 bb[2][8];   // B-fragment buffers, 1-tap-deep rotation

    #define ISSUE_G(g, kk) {                                                \
        int4 ob = moS[(kk) * 64 + px];                                      \
        g[0] = *(const uint4*)(ib + ob.x + chb);                            \
        g[1] = *(const uint4*)(ib + ob.x + chb + 64);                       \
        g[2] = *(const uint4*)(ib + ob.y + chb);                            \
        g[3] = *(const uint4*)(ib + ob.y + chb + 64);                       \
        g[4] = *(const uint4*)(ib + ob.z + chb);                            \
        g[5] = *(const uint4*)(ib + ob.z + chb + 64);                       \
        g[6] = *(const uint4*)(ib + ob.w + chb);                            \
        g[7] = *(const uint4*)(ib + ob.w + chb + 64);                       \
    }

    #define ISSUE_B(f, kk) {                                                \
        _Pragma("unroll")                                                   \
        for (int q = 0; q < 8; ++q)                                         \
            f[q] = *(const short8*)(wt + ((((kk) * 8 + q) * 64 + l) << 3)); \
    }

    #define CMB(dst_, a0, a1, a2, a3) {                                     \
        float vlo = wA.x*blo(a0) + wA.y*blo(a1) + wB.x*blo(a2) + wB.y*blo(a3); \
        float vhi = wA.x*bhi(a0) + wA.y*bhi(a1) + wB.x*bhi(a2) + wB.y*bhi(a3); \
        dst_ = __builtin_amdgcn_perm(__float_as_uint(vhi) + 0x8000u,        \
                                     __float_as_uint(vlo) + 0x8000u, 0x07060302u); }

    #define COMBINE_MFMA(g, kk, bfr) {                                      \
        uint2 wp = mwH[(kk) * 64 + px];                                     \
        float2 wA = __half22float2(*(const __half2*)&wp.x);                 \
        float2 wB = __half22float2(*(const __half2*)&wp.y);                 \
        short8 af[2];                                                       \
        _Pragma("unroll")                                                   \
        for (int kf = 0; kf < 2; ++kf) {                                    \
            uint4 c00 = g[0 + kf], c01 = g[2 + kf], c10 = g[4 + kf], c11 = g[6 + kf]; \
            unsigned r0, r1, r2, r3;                                        \
            CMB(r0, c00.x, c01.x, c10.x, c11.x);                            \
            CMB(r1, c00.y, c01.y, c10.y, c11.y);                            \
            CMB(r2, c00.z, c01.z, c10.z, c11.z);                            \
            CMB(r3, c00.w, c01.w, c10.w, c11.w);                            \
            union { unsigned u[4]; short8 s; } uu = {{r0, r1, r2, r3}};     \
            af[kf] = uu.s;                                                  \
        }                                                                   \
        _Pragma("unroll")                                                   \
        for (int cot = 0; cot < 4; ++cot) {                                 \
            acc[cot] = __builtin_amdgcn_mfma_f32_16x16x32_bf16(af[0], bfr[cot],     acc[cot], 0, 0, 0); \
            acc[cot] = __builtin_amdgcn_mfma_f32_16x16x32_bf16(af[1], bfr[4 + cot], acc[cot], 0, 0, 0); \
        }                                                                   \
    }

    // prologue: 2 tap-gathers + 1 B-frag set in flight
    ISSUE_G(gg[0], 0)
    ISSUE_B(bb[0], 0)
    ISSUE_G(gg[1], 1)

    #pragma unroll
    for (int k = 0; k < 9; ++k) {
        if (k < 8) { ISSUE_B(bb[(k + 1) & 1], k + 1) }
        if (k < 7) {
            if ((k + 2) % 3 == 0)      { ISSUE_G(gg[0], k + 2) }
            else if ((k + 2) % 3 == 1) { ISSUE_G(gg[1], k + 2) }
            else                       { ISSUE_G(gg[2], k + 2) }
        }
        __builtin_amdgcn_sched_barrier(0);   // pin: issues above, combine below
        if (k % 3 == 0)      { COMBINE_MFMA(gg[0], k, bb[k & 1]) }
        else if (k % 3 == 1) { COMBINE_MFMA(gg[1], k, bb[k & 1]) }
        else                 { COMBINE_MFMA(gg[2], k, bb[k & 1]) }
    }
    #undef ISSUE_G
    #undef ISSUE_B
    #undef CMB
    #undef COMBINE_MFMA

    // ---- epilogue: swizzled transpose through LDS, coalesced stores ----
    float* out_t = (float*)smem;   // [64 co][256 B rows], XOR-swizzled
    const int pxb = (wv << 6) + ((l >> 4) << 4);   // byte col of this lane's 4-px group
    const int swE = (l & 15) << 4;                 // co_e & 15 == l & 15
    __syncthreads();   // main-loop LDS reads done in all waves before overlay
    #pragma unroll
    for (int cot = 0; cot < 4; ++cot) {
        int co_e = (cot << 4) + (l & 15);
        float bv = bias[co_e];
        float4 v = make_float4(acc[cot][0] + bv, acc[cot][1] + bv,
                               acc[cot][2] + bv, acc[cot][3] + bv);
        *(float4*)((unsigned char*)out_t + co_e * 256 + (pxb ^ swE)) = v;
    }
    __syncthreads();
    float* outb = out + (size_t)b * 64 * HW + (size_t)ho * WW + wo0;
    #pragma unroll
    for (int j = 0; j < 4; ++j) {
        int co   = (t >> 4) + (j << 4);
        int colb = (t & 15) << 4;
        float4 v = *(const float4*)((const unsigned char*)out_t + co * 256 + (colb ^ ((co & 15) << 4)));
        *(float4*)&outb[(size_t)co * HW + ((t & 15) << 2)] = v;
    }
}

// -------- fallback (NCHW gather, raw weights) for tiny workspace --------
__global__ __launch_bounds__(256, 4) void deform_fallback(
    const float* __restrict__ x, const float* __restrict__ off,
    const float* __restrict__ msk, const float* __restrict__ wraw,
    const float* __restrict__ bias, float* __restrict__ out)
{
    __shared__ unsigned short s_tile[2][64][68];
    __shared__ __align__(16) unsigned char meta_mem[18432];
    float4* mwS = (float4*)meta_mem;
    int4*   moS = (int4*)(meta_mem + 9216);
    float*  out_t = (float*)meta_mem;

    const int t   = threadIdx.x;
    const int bid = blockIdx.x;
    const int b   = bid & 7;
    const int rem = bid >> 3;
    const int ho  = rem >> 1;
    const int wo0 = (rem & 1) << 6;
    const int l   = t & 63;
    const int wv_id = __builtin_amdgcn_readfirstlane(t >> 6);
    const int c0  = wv_id << 4;
    const int cb  = wv_id << 4;

    short8 wtf[2][2];
    #pragma unroll
    for (int kf = 0; kf < 2; ++kf) {
        short8 f;
        int co = cb + (l & 15);
        int cbase = kf * 32 + (l >> 4) * 8;
        #pragma unroll
        for (int e = 0; e < 8; ++e) f[e] = (short)f2bf(wraw[(co * 64 + cbase + e) * 9 + 0]);
        wtf[0][kf] = f;
    }

    for (int i = t; i < 9 * 64; i += 256) {
        int p = i & 63;
        int k = i >> 6;
        int wo = wo0 + p;
        int obase = ((b * 18 + 2 * k) * HH + ho) * WW + wo;
        float oy = off[obase];
        float ox = off[obase + HW];
        float m  = msk[((b * 9 + k) * HH + ho) * WW + wo];
        float py = oy + (float)(k / 3) + (float)(ho - 1);
        float px = ox + (float)(k % 3) + (float)(wo - 1);
        float fy = floorf(py), fx = floorf(px);
        float ly = py - fy,    lx = px - fx;
        int y0 = (int)fy, x0 = (int)fx;
        int y1 = y0 + 1,  x1 = x0 + 1;
        float vy0 = (y0 >= 0 && y0 < HH) ? 1.f : 0.f;
        float vy1 = (y1 >= 0 && y1 < HH) ? 1.f : 0.f;
        float vx0 = (x0 >= 0 && x0 < WW) ? 1.f : 0.f;
        float vx1 = (x1 >= 0 && x1 < WW) ? 1.f : 0.f;
        float w00 = (1.f - ly) * (1.f - lx) * m * vy0 * vx0;
        float w01 = (1.f - ly) * lx         * m * vy0 * vx1;
        float w10 = ly         * (1.f - lx) * m * vy1 * vx0;
        float w11 = ly         * lx         * m * vy1 * vx1;
        int yc0 = min(max(y0, 0), HH - 1), yc1 = min(max(y1, 0), HH - 1);
        int xc0 = min(max(x0, 0), WW - 1), xc1 = min(max(x1, 0), WW - 1);
        mwS[i] = make_float4(w00, w01, w10, w11);
        moS[i] = make_int4(yc0 * WW + xc0, yc0 * WW + xc1,
                           yc1 * WW + xc0, yc1 * WW + xc1);
    }

    const int p = t & 63;
    const float* xb = x + (size_t)(b * 64 + c0) * HW;
    __syncthreads();

    {
        float4 wv = mwS[p];
        int4   ov = moS[p];
        const float* pc = xb;
        #pragma unroll
        for (int i = 0; i < 16; i += 4) {
            float v0 = wv.x * pc[ov.x] + wv.y * pc[ov.y] + wv.z * pc[ov.z] + wv.w * pc[ov.w]; pc += HW;
            float v1 = wv.x * pc[ov.x] + wv.y * pc[ov.y] + wv.z * pc[ov.z] + wv.w * pc[ov.w]; pc += HW;
            float v2 = wv.x * pc[ov.x] + wv.y * pc[ov.y] + wv.z * pc[ov.z] + wv.w * pc[ov.w]; pc += HW;
            float v3 = wv.x * pc[ov.x] + wv.y * pc[ov.y] + wv.z * pc[ov.z] + wv.w * pc[ov.w]; pc += HW;
            uint2 u;
            u.x = (unsigned)f2bf(v0) | ((unsigned)f2bf(v1) << 16);
            u.y = (unsigned)f2bf(v2) | ((unsigned)f2bf(v3) << 16);
            *(uint2*)&s_tile[0][p][c0 + i] = u;
        }
    }
    __syncthreads();

    f32x4 acc[4];
    #pragma unroll
    for (int g = 0; g < 4; ++g) acc[g] = (f32x4){0.f, 0.f, 0.f, 0.f};

    #pragma unroll
    for (int s = 0; s < 9; ++s) {
        if (s < 8) {
            const int kn = s + 1;
            #pragma unroll
            for (int kf = 0; kf < 2; ++kf) {
                short8 f;
                int co = cb + (l & 15);
                int cbase = kf * 32 + (l >> 4) * 8;
                #pragma unroll
                for (int e = 0; e < 8; ++e) f[e] = (short)f2bf(wraw[(co * 64 + cbase + e) * 9 + kn]);
                wtf[kn & 1][kf] = f;
            }
            float4 wv = mwS[kn * 64 + p];
            int4   ov = moS[kn * 64 + p];
            const float* pc = xb;
            #pragma unroll
            for (int i = 0; i < 16; i += 4) {
                float v0 = wv.x * pc[ov.x] + wv.y * pc[ov.y] + wv.z * pc[ov.z] + wv.w * pc[ov.w]; pc += HW;
                float v1 = wv.x * pc[ov.x] + wv.y * pc[ov.y] + wv.z * pc[ov.z] + wv.w * pc[ov.w]; pc += HW;
                float v2 = wv.x * pc[ov.x] + wv.y * pc[ov.y] + wv.z * pc[ov.z] + wv.w * pc[ov.w]; pc += HW;
                float v3 = wv.x * pc[ov.x] + wv.y * pc[ov.y] + wv.z * pc[ov.z] + wv.w * pc[ov.w]; pc += HW;
                uint2 u;
                u.x = (unsigned)f2bf(v0) | ((unsigned)f2bf(v1) << 16);
                u.y = (unsigned)f2bf(v2) | ((unsigned)f2bf(v3) << 16);
                *(uint2*)&s_tile[kn & 1][p][c0 + i] = u;
            }
        }
        #pragma unroll
        for (int g = 0; g < 4; ++g) {
            const int prow = g * 16 + (l & 15);
            const unsigned short* rp = &s_tile[s & 1][prow][(l >> 4) * 8];
            union { short8 v; unsigned long long q[2]; } ua0, ua1;
            ua0.q[0] = *(const unsigned long long*)(rp);
            ua0.q[1] = *(const unsigned long long*)(rp + 4);
            ua1.q[0] = *(const unsigned long long*)(rp + 32);
            ua1.q[1] = *(const unsigned long long*)(rp + 36);
            acc[g] = __builtin_amdgcn_mfma_f32_16x16x32_bf16(ua0.v, wtf[s & 1][0], acc[g], 0, 0, 0);
            acc[g] = __builtin_amdgcn_mfma_f32_16x16x32_bf16(ua1.v, wtf[s & 1][1], acc[g], 0, 0, 0);
        }
        __syncthreads();
    }

    const float bv = bias[cb + (l & 15)];
    #pragma unroll
    for (int g = 0; g < 4; ++g) {
        int co = cb + (l & 15);
        int pxb = g * 16 + (l >> 4) * 4;
        #pragma unroll
        for (int r = 0; r < 4; ++r)
            out_t[co * 68 + pxb + r] = acc[g][r] + bv;
    }
    __syncthreads();
    float* outb = out + (size_t)b * 64 * HW + (size_t)ho * WW + wo0;
    #pragma unroll
    for (int j = 0; j < 4; ++j) {
        int co  = (t >> 4) + j * 16;
        int px0 = (t & 15) << 2;
        float4 v = *(float4*)&out_t[co * 68 + px0];
        *(float4*)&outb[(size_t)co * HW + px0] = v;
    }
}

extern "C" void kernel_launch(void* const* d_in, const int* in_sizes, int n_in,
                              void* d_out, int out_size, void* d_ws, size_t ws_size,
                              hipStream_t stream) {
    const float* x    = (const float*)d_in[0];
    const float* off  = (const float*)d_in[1];
    const float* msk  = (const float*)d_in[2];
    const float* w    = (const float*)d_in[3];
    const float* bias = (const float*)d_in[4];
    float* out = (float*)d_out;

    const size_t need = XT_BYTES + WT_BYTES;
    if (d_ws != nullptr && ws_size >= need) {
        unsigned int*   xt32 = (unsigned int*)d_ws;
        unsigned short* wt   = (unsigned short*)((char*)d_ws + XT_BYTES);
        xtrans_kernel<<<2048, 256, 0, stream>>>(x, xt32);
        wtrans_kernel<<<144, 256, 0, stream>>>(w, wt);
        deform_nhwc<<<2048, 256, 0, stream>>>((const unsigned short*)xt32, off, msk, wt, bias, out);
    } else {
        deform_fallback<<<2048, 256, 0, stream>>>(x, off, msk, w, bias, out);
    }
}

// Round 8
// 52.359 us; speedup vs baseline: 1.8592x; 1.8592x over previous
//
#include <hip/hip_runtime.h>
#include <hip/hip_fp16.h>

#define HH 128
#define WW 128
#define HW (HH*WW)
#define XT_BYTES ((size_t)8 * HW * 64 * 2)   // x_t bf16 NHWC
#define WT_BYTES ((size_t)9 * 2 * 4 * 64 * 8 * 2)

typedef __attribute__((ext_vector_type(8))) short short8;
typedef __attribute__((ext_vector_type(4))) float f32x4;
typedef __attribute__((ext_vector_type(2))) float f32x2;

static __device__ __forceinline__ unsigned short f2bf(float f) {
    unsigned int u = __float_as_uint(f);
    u += 0x7fffu + ((u >> 16) & 1u);
    return (unsigned short)(u >> 16);
}
static __device__ __forceinline__ f32x2 ub2(unsigned u) {   // packed 2xbf16 -> 2xf32
    f32x2 r;
    r.x = __uint_as_float(u << 16);
    r.y = __uint_as_float(u & 0xffff0000u);
    return r;
}
static __device__ __forceinline__ f32x2 spl(float f) { f32x2 r; r.x = f; r.y = f; return r; }

// weight (64,64,3,3) fp32 -> bf16 B-fragment layout wt[tap][kf][wave][lane][e]
__global__ void wtrans_kernel(const float* __restrict__ w, unsigned short* __restrict__ wt) {
    int i = blockIdx.x * 256 + threadIdx.x;
    if (i < 9 * 2 * 4 * 64 * 8) {
        int e  = i & 7;
        int l  = (i >> 3) & 63;
        int wv = (i >> 9) & 3;
        int kf = (i >> 11) & 1;
        int k  = i >> 12;
        int co = wv * 16 + (l & 15);
        int c  = kf * 32 + (l >> 4) * 8 + e;
        wt[i] = f2bf(w[(co * 64 + c) * 9 + k]);
    }
}

// x [8,64,128,128] f32 -> x_t [8,HW,64] bf16 (NHWC). Block: 64 hw x 64 ch.
__global__ __launch_bounds__(256) void xtrans_kernel(const float* __restrict__ x,
                                                     unsigned int* __restrict__ xt32) {
    __shared__ float tile[64][65];
    const int bid = blockIdx.x;
    const int b   = bid >> 8;
    const int hw0 = (bid & 255) << 6;
    const int t   = threadIdx.x;
    #pragma unroll
    for (int i = 0; i < 16; ++i) {
        int idx = (i << 8) + t;
        int c = idx >> 6, j = idx & 63;
        tile[c][j] = x[(size_t)(((b << 6) + c) << 14) + hw0 + j];
    }
    __syncthreads();
    #pragma unroll
    for (int i = 0; i < 8; ++i) {
        int idx = (i << 8) + t;
        int cp = idx & 31, hw = idx >> 5;
        unsigned u = (unsigned)f2bf(tile[2 * cp][hw]) | ((unsigned)f2bf(tile[2 * cp + 1][hw]) << 16);
        xt32[((size_t)((b << 14) + hw0 + hw) << 5) + cp] = u;
    }
}

// Fast path: block = 64 px (half row), 4 waves; wave w: px [16w,16w+16) sampling + couts [16w,16w+16) MFMA.
// Round-4 verified numerics (fp16 weight pairs, fp32 FMA combine, XOR-swizzled LDS).
// T14 stage order: ISSUE loads(k+1) -> MFMA(k) -> combine+store(k+1), sched_barrier(0) pins.
__global__ __launch_bounds__(256, 4) void deform_nhwc(
    const unsigned short* __restrict__ xt,  // [8][HW][64] bf16
    const float* __restrict__ off,
    const float* __restrict__ msk,
    const unsigned short* __restrict__ wt,  // packed bf16 B-fragments
    const float* __restrict__ bias,
    float* __restrict__ out)
{
    // [0,16384): two 8 KB sample buffers, XOR-swizzled [64 px][64 ch] bf16
    // [16384,25600): moS int4 corner byte-offsets [9*64]
    // [25600,30208): mwH packed fp16 bilinear weight pairs [9*64]
    // epilogue: [0,16384) reused as swizzled fp32 out_t
    __shared__ __align__(16) unsigned char smem[30208];
    int4*  moS = (int4*)(smem + 16384);
    uint2* mwH = (uint2*)(smem + 25600);

    const int t   = threadIdx.x;
    const int bid = blockIdx.x;
    const int b   = bid & 7;            // image <-> XCD affinity
    const int rem = bid >> 3;
    const int ho  = rem >> 1;
    const int wo0 = (rem & 1) << 6;
    const int l   = t & 63;
    const int wv  = __builtin_amdgcn_readfirstlane(t >> 6);

    // ---- per-(tap,pixel) metadata ----
    for (int i = t; i < 9 * 64; i += 256) {
        int p = i & 63;
        int k = i >> 6;
        int wo = wo0 + p;
        int obase = ((b * 18 + 2 * k) * HH + ho) * WW + wo;
        float oy = off[obase];
        float ox = off[obase + HW];
        float m  = msk[((b * 9 + k) * HH + ho) * WW + wo];
        float py = oy + (float)(k / 3) + (float)(ho - 1);
        float px = ox + (float)(k % 3) + (float)(wo - 1);
        float fy = floorf(py), fx = floorf(px);
        float ly = py - fy,    lx = px - fx;
        int y0 = (int)fy, x0 = (int)fx;
        int y1 = y0 + 1,  x1 = x0 + 1;
        float vy0 = (y0 >= 0 && y0 < HH) ? 1.f : 0.f;
        float vy1 = (y1 >= 0 && y1 < HH) ? 1.f : 0.f;
        float vx0 = (x0 >= 0 && x0 < WW) ? 1.f : 0.f;
        float vx1 = (x1 >= 0 && x1 < WW) ? 1.f : 0.f;
        float w00 = (1.f - ly) * (1.f - lx) * m * vy0 * vx0;
        float w01 = (1.f - ly) * lx         * m * vy0 * vx1;
        float w10 = ly         * (1.f - lx) * m * vy1 * vx0;
        float w11 = ly         * lx         * m * vy1 * vx1;
        int yc0 = min(max(y0, 0), HH - 1), yc1 = min(max(y1, 0), HH - 1);
        int xc0 = min(max(x0, 0), WW - 1), xc1 = min(max(x1, 0), WW - 1);
        moS[i] = make_int4((yc0 * WW + xc0) << 7, (yc0 * WW + xc1) << 7,
                           (yc1 * WW + xc0) << 7, (yc1 * WW + xc1) << 7);
        __half2 hA = __floats2half2_rn(w00, w01);
        __half2 hB = __floats2half2_rn(w10, w11);
        mwH[i] = make_uint2(*(unsigned int*)&hA, *(unsigned int*)&hB);
    }

    const char* ib   = (const char*)xt + (size_t)b * HW * 128;  // image base (bytes)
    const int  chb   = (l & 7) << 4;               // byte offset of this lane's 8 channels
    const int  px0_  = (wv << 4) + (l >> 3);       // r=0 pixel
    int st_woff[2];
    st_woff[0] = px0_ * 128 + (chb ^ ((px0_ & 7) << 4));
    st_woff[1] = st_woff[0] + 8 * 128;             // (px0_+8)&7 == px0_&7
    const int lq = (l >> 4) << 4;                  // fragment col-byte base
    const int sw = (l & 7) << 4;                   // read-side swizzle (prow&7 == l&7)

    uint4  g0[4], g1[4];   // in-flight gathers: [corner] for r=0 / r=1 pixels
    short8 wtf[2][2];      // rotating B-fragments

    #define ISSUE_TAP(kk) {                                          \
        int4 ob0 = moS[(kk) * 64 + px0_];                            \
        g0[0] = *(const uint4*)(ib + ob0.x + chb);                   \
        g0[1] = *(const uint4*)(ib + ob0.y + chb);                   \
        g0[2] = *(const uint4*)(ib + ob0.z + chb);                   \
        g0[3] = *(const uint4*)(ib + ob0.w + chb);                   \
        int4 ob1 = moS[(kk) * 64 + px0_ + 8];                        \
        g1[0] = *(const uint4*)(ib + ob1.x + chb);                   \
        g1[1] = *(const uint4*)(ib + ob1.y + chb);                   \
        g1[2] = *(const uint4*)(ib + ob1.z + chb);                   \
        g1[3] = *(const uint4*)(ib + ob1.w + chb);                   \
    }

    // round-4 verified combine (fp32 FMA on unpacked bf16, perm pack), f32x2-vectorized
    #define CMB_V(dst_, c00, c01, c10, c11) {                        \
        f32x2 v = spl(wA.x) * ub2(c00) + spl(wA.y) * ub2(c01)        \
                + spl(wB.x) * ub2(c10) + spl(wB.y) * ub2(c11);       \
        dst_ = __builtin_amdgcn_perm(__float_as_uint(v.y) + 0x8000u, \
                                     __float_as_uint(v.x) + 0x8000u, 0x07060302u); \
    }

    #define COMBINE_STORE(kk, dstb) {                                \
        {                                                            \
            uint2 wp = mwH[(kk) * 64 + px0_];                        \
            float2 wA = __half22float2(*(const __half2*)&wp.x);      \
            float2 wB = __half22float2(*(const __half2*)&wp.y);      \
            uint4 uv;                                                \
            CMB_V(uv.x, g0[0].x, g0[1].x, g0[2].x, g0[3].x)          \
            CMB_V(uv.y, g0[0].y, g0[1].y, g0[2].y, g0[3].y)          \
            CMB_V(uv.z, g0[0].z, g0[1].z, g0[2].z, g0[3].z)          \
            CMB_V(uv.w, g0[0].w, g0[1].w, g0[2].w, g0[3].w)          \
            *(uint4*)((dstb) + st_woff[0]) = uv;                     \
        }                                                            \
        {                                                            \
            uint2 wp = mwH[(kk) * 64 + px0_ + 8];                    \
            float2 wA = __half22float2(*(const __half2*)&wp.x);      \
            float2 wB = __half22float2(*(const __half2*)&wp.y);      \
            uint4 uv;                                                \
            CMB_V(uv.x, g1[0].x, g1[1].x, g1[2].x, g1[3].x)          \
            CMB_V(uv.y, g1[0].y, g1[1].y, g1[2].y, g1[3].y)          \
            CMB_V(uv.z, g1[0].z, g1[1].z, g1[2].z, g1[3].z)          \
            CMB_V(uv.w, g1[0].w, g1[1].w, g1[2].w, g1[3].w)          \
            *(uint4*)((dstb) + st_woff[1]) = uv;                     \
        }                                                            \
    }

    __syncthreads();   // meta visible

    // ---- prologue: tap 0 (no MFMA to hide under) ----
    ISSUE_TAP(0)
    #pragma unroll
    for (int kf = 0; kf < 2; ++kf)
        wtf[0][kf] = *(const short8*)(wt + (((kf * 4 + wv) * 64 + l) << 3));
    COMBINE_STORE(0, smem)
    __syncthreads();

    f32x4 acc[4];
    #pragma unroll
    for (int g = 0; g < 4; ++g) acc[g] = (f32x4){0.f, 0.f, 0.f, 0.f};

    // ---- 9 stages: issue(k+1) / MFMA(k) / combine(k+1), 1 sync each ----
    #pragma unroll
    for (int s = 0; s < 9; ++s) {
        if (s < 8) {
            const int kn = s + 1;
            ISSUE_TAP(kn)
            #pragma unroll
            for (int kf = 0; kf < 2; ++kf)
                wtf[kn & 1][kf] = *(const short8*)(wt + ((((kn * 2 + kf) * 4 + wv) * 64 + l) << 3));
        }
        __builtin_amdgcn_sched_barrier(0);   // loads stay above (issued early)
        {
            const unsigned char* rb = smem + ((s & 1) << 13);
            #pragma unroll
            for (int g = 0; g < 4; ++g) {
                const int prow = g * 16 + (l & 15);
                short8 a0 = *(const short8*)(rb + prow * 128 + (lq ^ sw));
                short8 a1 = *(const short8*)(rb + prow * 128 + ((64 + lq) ^ sw));
                acc[g] = __builtin_amdgcn_mfma_f32_16x16x32_bf16(a0, wtf[s & 1][0], acc[g], 0, 0, 0);
                acc[g] = __builtin_amdgcn_mfma_f32_16x16x32_bf16(a1, wtf[s & 1][1], acc[g], 0, 0, 0);
            }
        }
        __builtin_amdgcn_sched_barrier(0);   // vmcnt drain lands after the MFMAs
        if (s < 8) {
            COMBINE_STORE(s + 1, smem + (((s + 1) & 1) << 13))
        }
        __syncthreads();
    }
    #undef ISSUE_TAP
    #undef CMB_V
    #undef COMBINE_STORE

    // ---- epilogue: swizzled transpose through LDS, coalesced float4 stores ----
    float* out_t = (float*)smem;   // [64 co][256 B rows], XOR-swizzled
    const int cb = wv << 4;
    const int co_e = cb + (l & 15);
    const float bv = bias[co_e];
    const int swE = (co_e & 15) << 4;
    #pragma unroll
    for (int g = 0; g < 4; ++g) {
        int pxb = (g << 6) + ((l >> 4) << 4);   // byte col of pixel group
        float4 v = make_float4(acc[g][0] + bv, acc[g][1] + bv, acc[g][2] + bv, acc[g][3] + bv);
        *(float4*)((unsigned char*)out_t + co_e * 256 + (pxb ^ swE)) = v;
    }
    __syncthreads();
    float* outb = out + (size_t)b * 64 * HW + (size_t)ho * WW + wo0;
    #pragma unroll
    for (int j = 0; j < 4; ++j) {
        int co   = (t >> 4) + (j << 4);
        int colb = (t & 15) << 4;
        float4 v = *(const float4*)((const unsigned char*)out_t + co * 256 + (colb ^ ((co & 15) << 4)));
        *(float4*)&outb[(size_t)co * HW + ((t & 15) << 2)] = v;
    }
}

// -------- fallback (NCHW gather, raw weights) for tiny workspace --------
__global__ __launch_bounds__(256, 4) void deform_fallback(
    const float* __restrict__ x, const float* __restrict__ off,
    const float* __restrict__ msk, const float* __restrict__ wraw,
    const float* __restrict__ bias, float* __restrict__ out)
{
    __shared__ unsigned short s_tile[2][64][68];
    __shared__ __align__(16) unsigned char meta_mem[18432];
    float4* mwS = (float4*)meta_mem;
    int4*   moS = (int4*)(meta_mem + 9216);
    float*  out_t = (float*)meta_mem;

    const int t   = threadIdx.x;
    const int bid = blockIdx.x;
    const int b   = bid & 7;
    const int rem = bid >> 3;
    const int ho  = rem >> 1;
    const int wo0 = (rem & 1) << 6;
    const int l   = t & 63;
    const int wv_id = __builtin_amdgcn_readfirstlane(t >> 6);
    const int c0  = wv_id << 4;
    const int cb  = wv_id << 4;

    short8 wtf[2][2];
    #pragma unroll
    for (int kf = 0; kf < 2; ++kf) {
        short8 f;
        int co = cb + (l & 15);
        int cbase = kf * 32 + (l >> 4) * 8;
        #pragma unroll
        for (int e = 0; e < 8; ++e) f[e] = (short)f2bf(wraw[(co * 64 + cbase + e) * 9 + 0]);
        wtf[0][kf] = f;
    }

    for (int i = t; i < 9 * 64; i += 256) {
        int p = i & 63;
        int k = i >> 6;
        int wo = wo0 + p;
        int obase = ((b * 18 + 2 * k) * HH + ho) * WW + wo;
        float oy = off[obase];
        float ox = off[obase + HW];
        float m  = msk[((b * 9 + k) * HH + ho) * WW + wo];
        float py = oy + (float)(k / 3) + (float)(ho - 1);
        float px = ox + (float)(k % 3) + (float)(wo - 1);
        float fy = floorf(py), fx = floorf(px);
        float ly = py - fy,    lx = px - fx;
        int y0 = (int)fy, x0 = (int)fx;
        int y1 = y0 + 1,  x1 = x0 + 1;
        float vy0 = (y0 >= 0 && y0 < HH) ? 1.f : 0.f;
        float vy1 = (y1 >= 0 && y1 < HH) ? 1.f : 0.f;
        float vx0 = (x0 >= 0 && x0 < WW) ? 1.f : 0.f;
        float vx1 = (x1 >= 0 && x1 < WW) ? 1.f : 0.f;
        float w00 = (1.f - ly) * (1.f - lx) * m * vy0 * vx0;
        float w01 = (1.f - ly) * lx         * m * vy0 * vx1;
        float w10 = ly         * (1.f - lx) * m * vy1 * vx0;
        float w11 = ly         * lx         * m * vy1 * vx1;
        int yc0 = min(max(y0, 0), HH - 1), yc1 = min(max(y1, 0), HH - 1);
        int xc0 = min(max(x0, 0), WW - 1), xc1 = min(max(x1, 0), WW - 1);
        mwS[i] = make_float4(w00, w01, w10, w11);
        moS[i] = make_int4(yc0 * WW + xc0, yc0 * WW + xc1,
                           yc1 * WW + xc0, yc1 * WW + xc1);
    }

    const int p = t & 63;
    const float* xb = x + (size_t)(b * 64 + c0) * HW;
    __syncthreads();

    {
        float4 wv = mwS[p];
        int4   ov = moS[p];
        const float* pc = xb;
        #pragma unroll
        for (int i = 0; i < 16; i += 4) {
            float v0 = wv.x * pc[ov.x] + wv.y * pc[ov.y] + wv.z * pc[ov.z] + wv.w * pc[ov.w]; pc += HW;
            float v1 = wv.x * pc[ov.x] + wv.y * pc[ov.y] + wv.z * pc[ov.z] + wv.w * pc[ov.w]; pc += HW;
            float v2 = wv.x * pc[ov.x] + wv.y * pc[ov.y] + wv.z * pc[ov.z] + wv.w * pc[ov.w]; pc += HW;
            float v3 = wv.x * pc[ov.x] + wv.y * pc[ov.y] + wv.z * pc[ov.z] + wv.w * pc[ov.w]; pc += HW;
            uint2 u;
            u.x = (unsigned)f2bf(v0) | ((unsigned)f2bf(v1) << 16);
            u.y = (unsigned)f2bf(v2) | ((unsigned)f2bf(v3) << 16);
            *(uint2*)&s_tile[0][p][c0 + i] = u;
        }
    }
    __syncthreads();

    f32x4 acc[4];
    #pragma unroll
    for (int g = 0; g < 4; ++g) acc[g] = (f32x4){0.f, 0.f, 0.f, 0.f};

    #pragma unroll
    for (int s = 0; s < 9; ++s) {
        if (s < 8) {
            const int kn = s + 1;
            #pragma unroll
            for (int kf = 0; kf < 2; ++kf) {
                short8 f;
                int co = cb + (l & 15);
                int cbase = kf * 32 + (l >> 4) * 8;
                #pragma unroll
                for (int e = 0; e < 8; ++e) f[e] = (short)f2bf(wraw[(co * 64 + cbase + e) * 9 + kn]);
                wtf[kn & 1][kf] = f;
            }
            float4 wv = mwS[kn * 64 + p];
            int4   ov = moS[kn * 64 + p];
            const float* pc = xb;
            #pragma unroll
            for (int i = 0; i < 16; i += 4) {
                float v0 = wv.x * pc[ov.x] + wv.y * pc[ov.y] + wv.z * pc[ov.z] + wv.w * pc[ov.w]; pc += HW;
                float v1 = wv.x * pc[ov.x] + wv.y * pc[ov.y] + wv.z * pc[ov.z] + wv.w * pc[ov.w]; pc += HW;
                float v2 = wv.x * pc[ov.x] + wv.y * pc[ov.y] + wv.z * pc[ov.z] + wv.w * pc[ov.w]; pc += HW;
                float v3 = wv.x * pc[ov.x] + wv.y * pc[ov.y] + wv.z * pc[ov.z] + wv.w * pc[ov.w]; pc += HW;
                uint2 u;
                u.x = (unsigned)f2bf(v0) | ((unsigned)f2bf(v1) << 16);
                u.y = (unsigned)f2bf(v2) | ((unsigned)f2bf(v3) << 16);
                *(uint2*)&s_tile[kn & 1][p][c0 + i] = u;
            }
        }
        #pragma unroll
        for (int g = 0; g < 4; ++g) {
            const int prow = g * 16 + (l & 15);
            const unsigned short* rp = &s_tile[s & 1][prow][(l >> 4) * 8];
            union { short8 v; unsigned long long q[2]; } ua0, ua1;
            ua0.q[0] = *(const unsigned long long*)(rp);
            ua0.q[1] = *(const unsigned long long*)(rp + 4);
            ua1.q[0] = *(const unsigned long long*)(rp + 32);
            ua1.q[1] = *(const unsigned long long*)(rp + 36);
            acc[g] = __builtin_amdgcn_mfma_f32_16x16x32_bf16(ua0.v, wtf[s & 1][0], acc[g], 0, 0, 0);
            acc[g] = __builtin_amdgcn_mfma_f32_16x16x32_bf16(ua1.v, wtf[s & 1][1], acc[g], 0, 0, 0);
        }
        __syncthreads();
    }

    const float bv = bias[cb + (l & 15)];
    #pragma unroll
    for (int g = 0; g < 4; ++g) {
        int co = cb + (l & 15);
        int pxb = g * 16 + (l >> 4) * 4;
        #pragma unroll
        for (int r = 0; r < 4; ++r)
            out_t[co * 68 + pxb + r] = acc[g][r] + bv;
    }
    __syncthreads();
    float* outb = out + (size_t)b * 64 * HW + (size_t)ho * WW + wo0;
    #pragma unroll
    for (int j = 0; j < 4; ++j) {
        int co  = (t >> 4) + j * 16;
        int px0 = (t & 15) << 2;
        float4 v = *(float4*)&out_t[co * 68 + px0];
        *(float4*)&outb[(size_t)co * HW + px0] = v;
    }
}

extern "C" void kernel_launch(void* const* d_in, const int* in_sizes, int n_in,
                              void* d_out, int out_size, void* d_ws, size_t ws_size,
                              hipStream_t stream) {
    const float* x    = (const float*)d_in[0];
    const float* off  = (const float*)d_in[1];
    const float* msk  = (const float*)d_in[2];
    const float* w    = (const float*)d_in[3];
    const float* bias = (const float*)d_in[4];
    float* out = (float*)d_out;

    const size_t need = XT_BYTES + WT_BYTES;
    if (d_ws != nullptr && ws_size >= need) {
        unsigned int*   xt32 = (unsigned int*)d_ws;
        unsigned short* wt   = (unsigned short*)((char*)d_ws + XT_BYTES);
        xtrans_kernel<<<2048, 256, 0, stream>>>(x, xt32);
        wtrans_kernel<<<144, 256, 0, stream>>>(w, wt);
        deform_nhwc<<<2048, 256, 0, stream>>>((const unsigned short*)xt32, off, msk, wt, bias, out);
    } else {
        deform_fallback<<<2048, 256, 0, stream>>>(x, off, msk, w, bias, out);
    }
}

// Round 10
// 49.206 us; speedup vs baseline: 1.9784x; 1.0641x over previous
//
#include <hip/hip_runtime.h>
#include <hip/hip_fp16.h>

#define HH 128
#define WW 128
#define HW (HH*WW)
#define XT_BYTES ((size_t)8 * HW * 64 * 2)   // x_t f16 NHWC
#define WT_BYTES ((size_t)9 * 2 * 4 * 64 * 8 * 2)

typedef __attribute__((ext_vector_type(8))) short short8;
typedef __attribute__((ext_vector_type(4))) float f32x4;
typedef _Float16 half8 __attribute__((ext_vector_type(8)));

static __device__ __forceinline__ unsigned short f2bf(float f) {
    unsigned int u = __float_as_uint(f);
    u += 0x7fffu + ((u >> 16) & 1u);
    return (unsigned short)(u >> 16);
}
static __device__ __forceinline__ unsigned pkrtz(float lo, float hi) {
    auto r = __builtin_amdgcn_cvt_pkrtz(lo, hi);   // __fp16 ext_vector(2)
    return *(unsigned*)&r;
}

// weight (64,64,3,3) fp32 -> f16 B-fragment layout wt[tap][kf][wave][lane][e]
__global__ void wtrans_kernel(const float* __restrict__ w, unsigned short* __restrict__ wt) {
    int i = blockIdx.x * 256 + threadIdx.x;
    if (i < 9 * 2 * 4 * 64 * 8) {
        int e  = i & 7;
        int l  = (i >> 3) & 63;
        int wv = (i >> 9) & 3;
        int kf = (i >> 11) & 1;
        int k  = i >> 12;
        int co = wv * 16 + (l & 15);
        int c  = kf * 32 + (l >> 4) * 8 + e;
        __half hh = __float2half_rn(w[(co * 64 + c) * 9 + k]);
        wt[i] = __half_as_ushort(hh);
    }
}

// x [8,64,128,128] f32 -> x_t [8,HW,64] f16 (NHWC). Block: 64 hw x 64 ch.
__global__ __launch_bounds__(256) void xtrans_kernel(const float* __restrict__ x,
                                                     unsigned int* __restrict__ xt32) {
    __shared__ float tile[64][65];
    const int bid = blockIdx.x;
    const int b   = bid >> 8;
    const int hw0 = (bid & 255) << 6;
    const int t   = threadIdx.x;
    #pragma unroll
    for (int i = 0; i < 16; ++i) {
        int idx = (i << 8) + t;
        int c = idx >> 6, j = idx & 63;
        tile[c][j] = x[(size_t)(((b << 6) + c) << 14) + hw0 + j];
    }
    __syncthreads();
    #pragma unroll
    for (int i = 0; i < 8; ++i) {
        int idx = (i << 8) + t;
        int cp = idx & 31, hw = idx >> 5;
        xt32[((size_t)((b << 14) + hw0 + hw) << 5) + cp] =
            pkrtz(tile[2 * cp][hw], tile[2 * cp + 1][hw]);
    }
}

// f16 4-corner bilinear combine for 2 packed channels; v_fma_mix-friendly.
static __device__ __forceinline__ unsigned cmbf16(unsigned c00, unsigned c01,
                                                  unsigned c10, unsigned c11,
                                                  float w00, float w01,
                                                  float w10, float w11) {
    __half2 h00 = *(__half2*)&c00, h01 = *(__half2*)&c01;
    __half2 h10 = *(__half2*)&c10, h11 = *(__half2*)&c11;
    float vlo = fmaf(w00, __half2float(__low2half(h00)),
                fmaf(w01, __half2float(__low2half(h01)),
                fmaf(w10, __half2float(__low2half(h10)),
                     w11 * __half2float(__low2half(h11)))));
    float vhi = fmaf(w00, __half2float(__high2half(h00)),
                fmaf(w01, __half2float(__high2half(h01)),
                fmaf(w10, __half2float(__high2half(h10)),
                     w11 * __half2float(__high2half(h11)))));
    return pkrtz(vlo, vhi);
}

// Fast path: block = 64 px (half row), 4 waves; wave w: px [16w,16w+16) sampling + couts [16w,16w+16) MFMA.
// f16 staged image + f16 MFMA; r8 stage order: ISSUE loads(k+1) -> MFMA(k) -> combine+store(k+1).
__global__ __launch_bounds__(256, 4) void deform_nhwc(
    const unsigned short* __restrict__ xt,  // [8][HW][64] f16
    const float* __restrict__ off,
    const float* __restrict__ msk,
    const unsigned short* __restrict__ wt,  // packed f16 B-fragments
    const float* __restrict__ bias,
    float* __restrict__ out)
{
    // [0,16384): two 8 KB sample buffers, XOR-swizzled [64 px][64 ch] f16
    // [16384,25600): moS int4 corner byte-offsets [9*64]
    // [25600,30208): mwH packed fp16 bilinear weight pairs [9*64]
    // epilogue: [0,16384) reused as swizzled fp32 out_t
    __shared__ __align__(16) unsigned char smem[30208];
    int4*  moS = (int4*)(smem + 16384);
    uint2* mwH = (uint2*)(smem + 25600);

    const int t   = threadIdx.x;
    const int bid = blockIdx.x;
    const int b   = bid & 7;            // image <-> XCD affinity
    const int rem = bid >> 3;
    const int ho  = rem >> 1;
    const int wo0 = (rem & 1) << 6;
    const int l   = t & 63;
    const int wv  = __builtin_amdgcn_readfirstlane(t >> 6);

    // ---- per-(tap,pixel) metadata ----
    for (int i = t; i < 9 * 64; i += 256) {
        int p = i & 63;
        int k = i >> 6;
        int wo = wo0 + p;
        int obase = ((b * 18 + 2 * k) * HH + ho) * WW + wo;
        float oy = off[obase];
        float ox = off[obase + HW];
        float m  = msk[((b * 9 + k) * HH + ho) * WW + wo];
        float py = oy + (float)(k / 3) + (float)(ho - 1);
        float px = ox + (float)(k % 3) + (float)(wo - 1);
        float fy = floorf(py), fx = floorf(px);
        float ly = py - fy,    lx = px - fx;
        int y0 = (int)fy, x0 = (int)fx;
        int y1 = y0 + 1,  x1 = x0 + 1;
        float vy0 = (y0 >= 0 && y0 < HH) ? 1.f : 0.f;
        float vy1 = (y1 >= 0 && y1 < HH) ? 1.f : 0.f;
        float vx0 = (x0 >= 0 && x0 < WW) ? 1.f : 0.f;
        float vx1 = (x1 >= 0 && x1 < WW) ? 1.f : 0.f;
        float w00 = (1.f - ly) * (1.f - lx) * m * vy0 * vx0;
        float w01 = (1.f - ly) * lx         * m * vy0 * vx1;
        float w10 = ly         * (1.f - lx) * m * vy1 * vx0;
        float w11 = ly         * lx         * m * vy1 * vx1;
        int yc0 = min(max(y0, 0), HH - 1), yc1 = min(max(y1, 0), HH - 1);
        int xc0 = min(max(x0, 0), WW - 1), xc1 = min(max(x1, 0), WW - 1);
        moS[i] = make_int4((yc0 * WW + xc0) << 7, (yc0 * WW + xc1) << 7,
                           (yc1 * WW + xc0) << 7, (yc1 * WW + xc1) << 7);
        __half2 hA = __floats2half2_rn(w00, w01);
        __half2 hB = __floats2half2_rn(w10, w11);
        mwH[i] = make_uint2(*(unsigned int*)&hA, *(unsigned int*)&hB);
    }

    const char* ib   = (const char*)xt + (size_t)b * HW * 128;  // image base (bytes)
    const int  chb   = (l & 7) << 4;               // byte offset of this lane's 8 channels
    const int  px0_  = (wv << 4) + (l >> 3);       // r=0 pixel
    int st_woff[2];
    st_woff[0] = px0_ * 128 + (chb ^ ((px0_ & 7) << 4));
    st_woff[1] = st_woff[0] + 8 * 128;             // (px0_+8)&7 == px0_&7
    const int lq = (l >> 4) << 4;                  // fragment col-byte base
    const int sw = (l & 7) << 4;                   // read-side swizzle (prow&7 == l&7)

    uint4 g0[4], g1[4];    // in-flight gathers: [corner] for r=0 / r=1 pixels
    half8 wtf[2][2];       // rotating B-fragments

    #define ISSUE_TAP(kk) {                                          \
        int4 ob0 = moS[(kk) * 64 + px0_];                            \
        g0[0] = *(const uint4*)(ib + ob0.x + chb);                   \
        g0[1] = *(const uint4*)(ib + ob0.y + chb);                   \
        g0[2] = *(const uint4*)(ib + ob0.z + chb);                   \
        g0[3] = *(const uint4*)(ib + ob0.w + chb);                   \
        int4 ob1 = moS[(kk) * 64 + px0_ + 8];                        \
        g1[0] = *(const uint4*)(ib + ob1.x + chb);                   \
        g1[1] = *(const uint4*)(ib + ob1.y + chb);                   \
        g1[2] = *(const uint4*)(ib + ob1.z + chb);                   \
        g1[3] = *(const uint4*)(ib + ob1.w + chb);                   \
    }

    #define COMBINE_STORE(kk, dstb) {                                \
        {                                                            \
            uint2 wp = mwH[(kk) * 64 + px0_];                        \
            float2 wA = __half22float2(*(const __half2*)&wp.x);      \
            float2 wB = __half22float2(*(const __half2*)&wp.y);      \
            uint4 uv;                                                \
            uv.x = cmbf16(g0[0].x, g0[1].x, g0[2].x, g0[3].x, wA.x, wA.y, wB.x, wB.y); \
            uv.y = cmbf16(g0[0].y, g0[1].y, g0[2].y, g0[3].y, wA.x, wA.y, wB.x, wB.y); \
            uv.z = cmbf16(g0[0].z, g0[1].z, g0[2].z, g0[3].z, wA.x, wA.y, wB.x, wB.y); \
            uv.w = cmbf16(g0[0].w, g0[1].w, g0[2].w, g0[3].w, wA.x, wA.y, wB.x, wB.y); \
            *(uint4*)((dstb) + st_woff[0]) = uv;                     \
        }                                                            \
        {                                                            \
            uint2 wp = mwH[(kk) * 64 + px0_ + 8];                    \
            float2 wA = __half22float2(*(const __half2*)&wp.x);      \
            float2 wB = __half22float2(*(const __half2*)&wp.y);      \
            uint4 uv;                                                \
            uv.x = cmbf16(g1[0].x, g1[1].x, g1[2].x, g1[3].x, wA.x, wA.y, wB.x, wB.y); \
            uv.y = cmbf16(g1[0].y, g1[1].y, g1[2].y, g1[3].y, wA.x, wA.y, wB.x, wB.y); \
            uv.z = cmbf16(g1[0].z, g1[1].z, g1[2].z, g1[3].z, wA.x, wA.y, wB.x, wB.y); \
            uv.w = cmbf16(g1[0].w, g1[1].w, g1[2].w, g1[3].w, wA.x, wA.y, wB.x, wB.y); \
            *(uint4*)((dstb) + st_woff[1]) = uv;                     \
        }                                                            \
    }

    __syncthreads();   // meta visible

    // ---- prologue: tap 0 (no MFMA to hide under) ----
    ISSUE_TAP(0)
    #pragma unroll
    for (int kf = 0; kf < 2; ++kf) {
        short8 s = *(const short8*)(wt + (((kf * 4 + wv) * 64 + l) << 3));
        wtf[0][kf] = *(half8*)&s;
    }
    COMBINE_STORE(0, smem)
    __syncthreads();

    f32x4 acc[4];
    #pragma unroll
    for (int g = 0; g < 4; ++g) acc[g] = (f32x4){0.f, 0.f, 0.f, 0.f};

    // ---- 9 stages: issue(k+1) / MFMA(k) / combine(k+1), 1 sync each ----
    #pragma unroll
    for (int s = 0; s < 9; ++s) {
        if (s < 8) {
            const int kn = s + 1;
            ISSUE_TAP(kn)
            #pragma unroll
            for (int kf = 0; kf < 2; ++kf) {
                short8 sv = *(const short8*)(wt + ((((kn * 2 + kf) * 4 + wv) * 64 + l) << 3));
                wtf[kn & 1][kf] = *(half8*)&sv;
            }
        }
        __builtin_amdgcn_sched_barrier(0);   // loads stay above (issued early)
        {
            const unsigned char* rb = smem + ((s & 1) << 13);
            #pragma unroll
            for (int g = 0; g < 4; ++g) {
                const int prow = g * 16 + (l & 15);
                short8 a0 = *(const short8*)(rb + prow * 128 + (lq ^ sw));
                short8 a1 = *(const short8*)(rb + prow * 128 + ((64 + lq) ^ sw));
                acc[g] = __builtin_amdgcn_mfma_f32_16x16x32_f16(*(half8*)&a0, wtf[s & 1][0], acc[g], 0, 0, 0);
                acc[g] = __builtin_amdgcn_mfma_f32_16x16x32_f16(*(half8*)&a1, wtf[s & 1][1], acc[g], 0, 0, 0);
            }
        }
        __builtin_amdgcn_sched_barrier(0);   // vmcnt drain lands after the MFMAs
        if (s < 8) {
            COMBINE_STORE(s + 1, smem + (((s + 1) & 1) << 13))
        }
        __syncthreads();
    }
    #undef ISSUE_TAP
    #undef COMBINE_STORE

    // ---- epilogue: swizzled transpose through LDS, coalesced float4 stores ----
    float* out_t = (float*)smem;   // [64 co][256 B rows], XOR-swizzled
    const int cb = wv << 4;
    const int co_e = cb + (l & 15);
    const float bv = bias[co_e];
    const int swE = (co_e & 15) << 4;
    #pragma unroll
    for (int g = 0; g < 4; ++g) {
        int pxb = (g << 6) + ((l >> 4) << 4);   // byte col of pixel group
        float4 v = make_float4(acc[g][0] + bv, acc[g][1] + bv, acc[g][2] + bv, acc[g][3] + bv);
        *(float4*)((unsigned char*)out_t + co_e * 256 + (pxb ^ swE)) = v;
    }
    __syncthreads();
    float* outb = out + (size_t)b * 64 * HW + (size_t)ho * WW + wo0;
    #pragma unroll
    for (int j = 0; j < 4; ++j) {
        int co   = (t >> 4) + (j << 4);
        int colb = (t & 15) << 4;
        float4 v = *(const float4*)((const unsigned char*)out_t + co * 256 + (colb ^ ((co & 15) << 4)));
        *(float4*)&outb[(size_t)co * HW + ((t & 15) << 2)] = v;
    }
}

// -------- fallback (NCHW gather, raw weights, bf16 MFMA) for tiny workspace --------
__global__ __launch_bounds__(256, 4) void deform_fallback(
    const float* __restrict__ x, const float* __restrict__ off,
    const float* __restrict__ msk, const float* __restrict__ wraw,
    const float* __restrict__ bias, float* __restrict__ out)
{
    __shared__ unsigned short s_tile[2][64][68];
    __shared__ __align__(16) unsigned char meta_mem[18432];
    float4* mwS = (float4*)meta_mem;
    int4*   moS = (int4*)(meta_mem + 9216);
    float*  out_t = (float*)meta_mem;

    const int t   = threadIdx.x;
    const int bid = blockIdx.x;
    const int b   = bid & 7;
    const int rem = bid >> 3;
    const int ho  = rem >> 1;
    const int wo0 = (rem & 1) << 6;
    const int l   = t & 63;
    const int wv_id = __builtin_amdgcn_readfirstlane(t >> 6);
    const int c0  = wv_id << 4;
    const int cb  = wv_id << 4;

    short8 wtf[2][2];
    #pragma unroll
    for (int kf = 0; kf < 2; ++kf) {
        short8 f;
        int co = cb + (l & 15);
        int cbase = kf * 32 + (l >> 4) * 8;
        #pragma unroll
        for (int e = 0; e < 8; ++e) f[e] = (short)f2bf(wraw[(co * 64 + cbase + e) * 9 + 0]);
        wtf[0][kf] = f;
    }

    for (int i = t; i < 9 * 64; i += 256) {
        int p = i & 63;
        int k = i >> 6;
        int wo = wo0 + p;
        int obase = ((b * 18 + 2 * k) * HH + ho) * WW + wo;
        float oy = off[obase];
        float ox = off[obase + HW];
        float m  = msk[((b * 9 + k) * HH + ho) * WW + wo];
        float py = oy + (float)(k / 3) + (float)(ho - 1);
        float px = ox + (float)(k % 3) + (float)(wo - 1);
        float fy = floorf(py), fx = floorf(px);
        float ly = py - fy,    lx = px - fx;
        int y0 = (int)fy, x0 = (int)fx;
        int y1 = y0 + 1,  x1 = x0 + 1;
        float vy0 = (y0 >= 0 && y0 < HH) ? 1.f : 0.f;
        float vy1 = (y1 >= 0 && y1 < HH) ? 1.f : 0.f;
        float vx0 = (x0 >= 0 && x0 < WW) ? 1.f : 0.f;
        float vx1 = (x1 >= 0 && x1 < WW) ? 1.f : 0.f;
        float w00 = (1.f - ly) * (1.f - lx) * m * vy0 * vx0;
        float w01 = (1.f - ly) * lx         * m * vy0 * vx1;
        float w10 = ly         * (1.f - lx) * m * vy1 * vx0;
        float w11 = ly         * lx         * m * vy1 * vx1;
        int yc0 = min(max(y0, 0), HH - 1), yc1 = min(max(y1, 0), HH - 1);
        int xc0 = min(max(x0, 0), WW - 1), xc1 = min(max(x1, 0), WW - 1);
        mwS[i] = make_float4(w00, w01, w10, w11);
        moS[i] = make_int4(yc0 * WW + xc0, yc0 * WW + xc1,
                           yc1 * WW + xc0, yc1 * WW + xc1);
    }

    const int p = t & 63;
    const float* xb = x + (size_t)(b * 64 + c0) * HW;
    __syncthreads();

    {
        float4 wv = mwS[p];
        int4   ov = moS[p];
        const float* pc = xb;
        #pragma unroll
        for (int i = 0; i < 16; i += 4) {
            float v0 = wv.x * pc[ov.x] + wv.y * pc[ov.y] + wv.z * pc[ov.z] + wv.w * pc[ov.w]; pc += HW;
            float v1 = wv.x * pc[ov.x] + wv.y * pc[ov.y] + wv.z * pc[ov.z] + wv.w * pc[ov.w]; pc += HW;
            float v2 = wv.x * pc[ov.x] + wv.y * pc[ov.y] + wv.z * pc[ov.z] + wv.w * pc[ov.w]; pc += HW;
            float v3 = wv.x * pc[ov.x] + wv.y * pc[ov.y] + wv.z * pc[ov.z] + wv.w * pc[ov.w]; pc += HW;
            uint2 u;
            u.x = (unsigned)f2bf(v0) | ((unsigned)f2bf(v1) << 16);
            u.y = (unsigned)f2bf(v2) | ((unsigned)f2bf(v3) << 16);
            *(uint2*)&s_tile[0][p][c0 + i] = u;
        }
    }
    __syncthreads();

    f32x4 acc[4];
    #pragma unroll
    for (int g = 0; g < 4; ++g) acc[g] = (f32x4){0.f, 0.f, 0.f, 0.f};

    #pragma unroll
    for (int s = 0; s < 9; ++s) {
        if (s < 8) {
            const int kn = s + 1;
            #pragma unroll
            for (int kf = 0; kf < 2; ++kf) {
                short8 f;
                int co = cb + (l & 15);
                int cbase = kf * 32 + (l >> 4) * 8;
                #pragma unroll
                for (int e = 0; e < 8; ++e) f[e] = (short)f2bf(wraw[(co * 64 + cbase + e) * 9 + kn]);
                wtf[kn & 1][kf] = f;
            }
            float4 wv = mwS[kn * 64 + p];
            int4   ov = moS[kn * 64 + p];
            const float* pc = xb;
            #pragma unroll
            for (int i = 0; i < 16; i += 4) {
                float v0 = wv.x * pc[ov.x] + wv.y * pc[ov.y] + wv.z * pc[ov.z] + wv.w * pc[ov.w]; pc += HW;
                float v1 = wv.x * pc[ov.x] + wv.y * pc[ov.y] + wv.z * pc[ov.z] + wv.w * pc[ov.w]; pc += HW;
                float v2 = wv.x * pc[ov.x] + wv.y * pc[ov.y] + wv.z * pc[ov.z] + wv.w * pc[ov.w]; pc += HW;
                float v3 = wv.x * pc[ov.x] + wv.y * pc[ov.y] + wv.z * pc[ov.z] + wv.w * pc[ov.w]; pc += HW;
                uint2 u;
                u.x = (unsigned)f2bf(v0) | ((unsigned)f2bf(v1) << 16);
                u.y = (unsigned)f2bf(v2) | ((unsigned)f2bf(v3) << 16);
                *(uint2*)&s_tile[kn & 1][p][c0 + i] = u;
            }
        }
        #pragma unroll
        for (int g = 0; g < 4; ++g) {
            const int prow = g * 16 + (l & 15);
            const unsigned short* rp = &s_tile[s & 1][prow][(l >> 4) * 8];
            union { short8 v; unsigned long long q[2]; } ua0, ua1;
            ua0.q[0] = *(const unsigned long long*)(rp);
            ua0.q[1] = *(const unsigned long long*)(rp + 4);
            ua1.q[0] = *(const unsigned long long*)(rp + 32);
            ua1.q[1] = *(const unsigned long long*)(rp + 36);
            acc[g] = __builtin_amdgcn_mfma_f32_16x16x32_bf16(ua0.v, wtf[s & 1][0], acc[g], 0, 0, 0);
            acc[g] = __builtin_amdgcn_mfma_f32_16x16x32_bf16(ua1.v, wtf[s & 1][1], acc[g], 0, 0, 0);
        }
        __syncthreads();
    }

    const float bv = bias[cb + (l & 15)];
    #pragma unroll
    for (int g = 0; g < 4; ++g) {
        int co = cb + (l & 15);
        int pxb = g * 16 + (l >> 4) * 4;
        #pragma unroll
        for (int r = 0; r < 4; ++r)
            out_t[co * 68 + pxb + r] = acc[g][r] + bv;
    }
    __syncthreads();
    float* outb = out + (size_t)b * 64 * HW + (size_t)ho * WW + wo0;
    #pragma unroll
    for (int j = 0; j < 4; ++j) {
        int co  = (t >> 4) + j * 16;
        int px0 = (t & 15) << 2;
        float4 v = *(float4*)&out_t[co * 68 + px0];
        *(float4*)&outb[(size_t)co * HW + px0] = v;
    }
}

extern "C" void kernel_launch(void* const* d_in, const int* in_sizes, int n_in,
                              void* d_out, int out_size, void* d_ws, size_t ws_size,
                              hipStream_t stream) {
    const float* x    = (const float*)d_in[0];
    const float* off  = (const float*)d_in[1];
    const float* msk  = (const float*)d_in[2];
    const float* w    = (const float*)d_in[3];
    const float* bias = (const float*)d_in[4];
    float* out = (float*)d_out;

    const size_t need = XT_BYTES + WT_BYTES;
    if (d_ws != nullptr && ws_size >= need) {
        unsigned int*   xt32 = (unsigned int*)d_ws;
        unsigned short* wt   = (unsigned short*)((char*)d_ws + XT_BYTES);
        xtrans_kernel<<<2048, 256, 0, stream>>>(x, xt32);
        wtrans_kernel<<<144, 256, 0, stream>>>(w, wt);
        deform_nhwc<<<2048, 256, 0, stream>>>((const unsigned short*)xt32, off, msk, wt, bias, out);
    } else {
        deform_fallback<<<2048, 256, 0, stream>>>(x, off, msk, w, bias, out);
    }
}

// Round 11
// 49.180 us; speedup vs baseline: 1.9794x; 1.0005x over previous
//
#include <hip/hip_runtime.h>
#include <hip/hip_fp16.h>

#define HH 128
#define WW 128
#define HW (HH*WW)
#define XT_BYTES ((size_t)8 * HW * 64 * 2)   // x_t f16 NHWC
#define WT_BYTES ((size_t)9 * 2 * 4 * 64 * 8 * 2)

typedef __attribute__((ext_vector_type(8))) short short8;
typedef __attribute__((ext_vector_type(4))) float f32x4;
typedef _Float16 half8 __attribute__((ext_vector_type(8)));

static __device__ __forceinline__ unsigned short f2bf(float f) {
    unsigned int u = __float_as_uint(f);
    u += 0x7fffu + ((u >> 16) & 1u);
    return (unsigned short)(u >> 16);
}
static __device__ __forceinline__ unsigned pkrtz(float lo, float hi) {
    auto r = __builtin_amdgcn_cvt_pkrtz(lo, hi);   // __fp16 ext_vector(2)
    return *(unsigned*)&r;
}

// weight (64,64,3,3) fp32 -> f16 B-fragment layout wt[tap][kf][wave][lane][e]
__global__ void wtrans_kernel(const float* __restrict__ w, unsigned short* __restrict__ wt) {
    int i = blockIdx.x * 256 + threadIdx.x;
    if (i < 9 * 2 * 4 * 64 * 8) {
        int e  = i & 7;
        int l  = (i >> 3) & 63;
        int wv = (i >> 9) & 3;
        int kf = (i >> 11) & 1;
        int k  = i >> 12;
        int co = wv * 16 + (l & 15);
        int c  = kf * 32 + (l >> 4) * 8 + e;
        __half hh = __float2half_rn(w[(co * 64 + c) * 9 + k]);
        wt[i] = __half_as_ushort(hh);
    }
}

// x [8,64,128,128] f32 -> x_t [8,HW,64] f16 (NHWC). Block: 64 hw x 64 ch.
__global__ __launch_bounds__(256) void xtrans_kernel(const float* __restrict__ x,
                                                     unsigned int* __restrict__ xt32) {
    __shared__ float tile[64][65];
    const int bid = blockIdx.x;
    const int b   = bid >> 8;
    const int hw0 = (bid & 255) << 6;
    const int t   = threadIdx.x;
    #pragma unroll
    for (int i = 0; i < 16; ++i) {
        int idx = (i << 8) + t;
        int c = idx >> 6, j = idx & 63;
        tile[c][j] = x[(size_t)(((b << 6) + c) << 14) + hw0 + j];
    }
    __syncthreads();
    #pragma unroll
    for (int i = 0; i < 8; ++i) {
        int idx = (i << 8) + t;
        int cp = idx & 31, hw = idx >> 5;
        xt32[((size_t)((b << 14) + hw0 + hw) << 5) + cp] =
            pkrtz(tile[2 * cp][hw], tile[2 * cp + 1][hw]);
    }
}

// f16 4-corner bilinear combine for 2 packed channels; v_fma_mix-friendly.
static __device__ __forceinline__ unsigned cmbf16(unsigned c00, unsigned c01,
                                                  unsigned c10, unsigned c11,
                                                  float w00, float w01,
                                                  float w10, float w11) {
    __half2 h00 = *(__half2*)&c00, h01 = *(__half2*)&c01;
    __half2 h10 = *(__half2*)&c10, h11 = *(__half2*)&c11;
    float vlo = fmaf(w00, __half2float(__low2half(h00)),
                fmaf(w01, __half2float(__low2half(h01)),
                fmaf(w10, __half2float(__low2half(h10)),
                     w11 * __half2float(__low2half(h11)))));
    float vhi = fmaf(w00, __half2float(__high2half(h00)),
                fmaf(w01, __half2float(__high2half(h01)),
                fmaf(w10, __half2float(__high2half(h10)),
                     w11 * __half2float(__high2half(h11)))));
    return pkrtz(vlo, vhi);
}

// Fast path: block = 64 px (half row), 4 waves; wave w: px [16w,16w+16) sampling + couts [16w,16w+16) MFMA.
// 2-stage pipeline: ISSUE(tap s+2) -> MFMA(tap s) -> COMBINE(tap s+1); loads live a full
// barrier interval (cross-stage liveness is what actually defeats compiler load-sinking; r6 evidence).
__global__ __launch_bounds__(256, 4) void deform_nhwc(
    const unsigned short* __restrict__ xt,  // [8][HW][64] f16
    const float* __restrict__ off,
    const float* __restrict__ msk,
    const unsigned short* __restrict__ wt,  // packed f16 B-fragments
    const float* __restrict__ bias,
    float* __restrict__ out)
{
    // [0,16384): two 8 KB sample buffers, XOR-swizzled [64 px][64 ch] f16
    // [16384,25600): moS int4 corner byte-offsets [9*64]
    // [25600,30208): mwH packed fp16 bilinear weight pairs [9*64]
    // epilogue: [0,16384) reused as swizzled fp32 out_t
    __shared__ __align__(16) unsigned char smem[30208];
    int4*  moS = (int4*)(smem + 16384);
    uint2* mwH = (uint2*)(smem + 25600);

    const int t   = threadIdx.x;
    const int bid = blockIdx.x;
    const int b   = bid & 7;            // image <-> XCD affinity
    const int rem = bid >> 3;
    const int ho  = rem >> 1;
    const int wo0 = (rem & 1) << 6;
    const int l   = t & 63;
    const int wv  = __builtin_amdgcn_readfirstlane(t >> 6);

    // ---- per-(tap,pixel) metadata ----
    for (int i = t; i < 9 * 64; i += 256) {
        int p = i & 63;
        int k = i >> 6;
        int wo = wo0 + p;
        int obase = ((b * 18 + 2 * k) * HH + ho) * WW + wo;
        float oy = off[obase];
        float ox = off[obase + HW];
        float m  = msk[((b * 9 + k) * HH + ho) * WW + wo];
        float py = oy + (float)(k / 3) + (float)(ho - 1);
        float px = ox + (float)(k % 3) + (float)(wo - 1);
        float fy = floorf(py), fx = floorf(px);
        float ly = py - fy,    lx = px - fx;
        int y0 = (int)fy, x0 = (int)fx;
        int y1 = y0 + 1,  x1 = x0 + 1;
        float vy0 = (y0 >= 0 && y0 < HH) ? 1.f : 0.f;
        float vy1 = (y1 >= 0 && y1 < HH) ? 1.f : 0.f;
        float vx0 = (x0 >= 0 && x0 < WW) ? 1.f : 0.f;
        float vx1 = (x1 >= 0 && x1 < WW) ? 1.f : 0.f;
        float w00 = (1.f - ly) * (1.f - lx) * m * vy0 * vx0;
        float w01 = (1.f - ly) * lx         * m * vy0 * vx1;
        float w10 = ly         * (1.f - lx) * m * vy1 * vx0;
        float w11 = ly         * lx         * m * vy1 * vx1;
        int yc0 = min(max(y0, 0), HH - 1), yc1 = min(max(y1, 0), HH - 1);
        int xc0 = min(max(x0, 0), WW - 1), xc1 = min(max(x1, 0), WW - 1);
        moS[i] = make_int4((yc0 * WW + xc0) << 7, (yc0 * WW + xc1) << 7,
                           (yc1 * WW + xc0) << 7, (yc1 * WW + xc1) << 7);
        __half2 hA = __floats2half2_rn(w00, w01);
        __half2 hB = __floats2half2_rn(w10, w11);
        mwH[i] = make_uint2(*(unsigned int*)&hA, *(unsigned int*)&hB);
    }

    const char* ib   = (const char*)xt + (size_t)b * HW * 128;  // image base (bytes)
    const int  chb   = (l & 7) << 4;               // byte offset of this lane's 8 channels
    const int  px0_  = (wv << 4) + (l >> 3);       // r=0 pixel
    int st_woff[2];
    st_woff[0] = px0_ * 128 + (chb ^ ((px0_ & 7) << 4));
    st_woff[1] = st_woff[0] + 8 * 128;             // (px0_+8)&7 == px0_&7
    const int lq = (l >> 4) << 4;                  // fragment col-byte base
    const int sw = (l & 7) << 4;                   // read-side swizzle (prow&7 == l&7)

    uint4 gg0[2][4], gg1[2][4];   // 2 rotating in-flight gather sets (compile-time indexed)
    half8 wtf[2][2];              // rotating B-fragments

    #define ISSUE_TAP(kk, S) {                                       \
        int4 ob0 = moS[(kk) * 64 + px0_];                            \
        gg0[S][0] = *(const uint4*)(ib + ob0.x + chb);               \
        gg0[S][1] = *(const uint4*)(ib + ob0.y + chb);               \
        gg0[S][2] = *(const uint4*)(ib + ob0.z + chb);               \
        gg0[S][3] = *(const uint4*)(ib + ob0.w + chb);               \
        int4 ob1 = moS[(kk) * 64 + px0_ + 8];                        \
        gg1[S][0] = *(const uint4*)(ib + ob1.x + chb);               \
        gg1[S][1] = *(const uint4*)(ib + ob1.y + chb);               \
        gg1[S][2] = *(const uint4*)(ib + ob1.z + chb);               \
        gg1[S][3] = *(const uint4*)(ib + ob1.w + chb);               \
    }

    #define COMBINE_STORE(kk, S, dstb) {                             \
        {                                                            \
            uint2 wp = mwH[(kk) * 64 + px0_];                        \
            float2 wA = __half22float2(*(const __half2*)&wp.x);      \
            float2 wB = __half22float2(*(const __half2*)&wp.y);      \
            uint4 uv;                                                \
            uv.x = cmbf16(gg0[S][0].x, gg0[S][1].x, gg0[S][2].x, gg0[S][3].x, wA.x, wA.y, wB.x, wB.y); \
            uv.y = cmbf16(gg0[S][0].y, gg0[S][1].y, gg0[S][2].y, gg0[S][3].y, wA.x, wA.y, wB.x, wB.y); \
            uv.z = cmbf16(gg0[S][0].z, gg0[S][1].z, gg0[S][2].z, gg0[S][3].z, wA.x, wA.y, wB.x, wB.y); \
            uv.w = cmbf16(gg0[S][0].w, gg0[S][1].w, gg0[S][2].w, gg0[S][3].w, wA.x, wA.y, wB.x, wB.y); \
            *(uint4*)((dstb) + st_woff[0]) = uv;                     \
        }                                                            \
        {                                                            \
            uint2 wp = mwH[(kk) * 64 + px0_ + 8];                    \
            float2 wA = __half22float2(*(const __half2*)&wp.x);      \
            float2 wB = __half22float2(*(const __half2*)&wp.y);      \
            uint4 uv;                                                \
            uv.x = cmbf16(gg1[S][0].x, gg1[S][1].x, gg1[S][2].x, gg1[S][3].x, wA.x, wA.y, wB.x, wB.y); \
            uv.y = cmbf16(gg1[S][0].y, gg1[S][1].y, gg1[S][2].y, gg1[S][3].y, wA.x, wA.y, wB.x, wB.y); \
            uv.z = cmbf16(gg1[S][0].z, gg1[S][1].z, gg1[S][2].z, gg1[S][3].z, wA.x, wA.y, wB.x, wB.y); \
            uv.w = cmbf16(gg1[S][0].w, gg1[S][1].w, gg1[S][2].w, gg1[S][3].w, wA.x, wA.y, wB.x, wB.y); \
            *(uint4*)((dstb) + st_woff[1]) = uv;                     \
        }                                                            \
    }

    __syncthreads();   // meta visible

    // ---- prologue: tap 0 combine exposed once; tap 1 issued before first stage ----
    ISSUE_TAP(0, 0)
    #pragma unroll
    for (int kf = 0; kf < 2; ++kf) {
        short8 s = *(const short8*)(wt + (((kf * 4 + wv) * 64 + l) << 3));
        wtf[0][kf] = *(half8*)&s;
    }
    COMBINE_STORE(0, 0, smem)
    ISSUE_TAP(1, 1)
    __syncthreads();

    f32x4 acc[4];
    #pragma unroll
    for (int g = 0; g < 4; ++g) acc[g] = (f32x4){0.f, 0.f, 0.f, 0.f};

    // ---- 9 stages: ISSUE(s+2) / MFMA(s) / COMBINE(s+1), 1 sync each ----
    #pragma unroll
    for (int s = 0; s < 9; ++s) {
        if (s < 7) { ISSUE_TAP(s + 2, s & 1) }   // into the set freed last stage
        if (s < 8) {
            const int kn = s + 1;
            #pragma unroll
            for (int kf = 0; kf < 2; ++kf) {
                short8 sv = *(const short8*)(wt + ((((kn * 2 + kf) * 4 + wv) * 64 + l) << 3));
                wtf[kn & 1][kf] = *(half8*)&sv;
            }
        }
        __builtin_amdgcn_sched_barrier(0);   // issues stay above
        {
            const unsigned char* rb = smem + ((s & 1) << 13);
            #pragma unroll
            for (int g = 0; g < 4; ++g) {
                const int prow = g * 16 + (l & 15);
                short8 a0 = *(const short8*)(rb + prow * 128 + (lq ^ sw));
                short8 a1 = *(const short8*)(rb + prow * 128 + ((64 + lq) ^ sw));
                acc[g] = __builtin_amdgcn_mfma_f32_16x16x32_f16(*(half8*)&a0, wtf[s & 1][0], acc[g], 0, 0, 0);
                acc[g] = __builtin_amdgcn_mfma_f32_16x16x32_f16(*(half8*)&a1, wtf[s & 1][1], acc[g], 0, 0, 0);
            }
        }
        __builtin_amdgcn_sched_barrier(0);
        if (s < 8) {
            COMBINE_STORE(s + 1, (s + 1) & 1, smem + (((s + 1) & 1) << 13))
        }
        __syncthreads();
    }
    #undef ISSUE_TAP
    #undef COMBINE_STORE

    // ---- epilogue: swizzled transpose through LDS, coalesced float4 stores ----
    float* out_t = (float*)smem;   // [64 co][256 B rows], XOR-swizzled
    const int cb = wv << 4;
    const int co_e = cb + (l & 15);
    const float bv = bias[co_e];
    const int swE = (co_e & 15) << 4;
    #pragma unroll
    for (int g = 0; g < 4; ++g) {
        int pxb = (g << 6) + ((l >> 4) << 4);   // byte col of pixel group
        float4 v = make_float4(acc[g][0] + bv, acc[g][1] + bv, acc[g][2] + bv, acc[g][3] + bv);
        *(float4*)((unsigned char*)out_t + co_e * 256 + (pxb ^ swE)) = v;
    }
    __syncthreads();
    float* outb = out + (size_t)b * 64 * HW + (size_t)ho * WW + wo0;
    #pragma unroll
    for (int j = 0; j < 4; ++j) {
        int co   = (t >> 4) + (j << 4);
        int colb = (t & 15) << 4;
        float4 v = *(const float4*)((const unsigned char*)out_t + co * 256 + (colb ^ ((co & 15) << 4)));
        *(float4*)&outb[(size_t)co * HW + ((t & 15) << 2)] = v;
    }
}

// -------- fallback (NCHW gather, raw weights, bf16 MFMA) for tiny workspace --------
__global__ __launch_bounds__(256, 4) void deform_fallback(
    const float* __restrict__ x, const float* __restrict__ off,
    const float* __restrict__ msk, const float* __restrict__ wraw,
    const float* __restrict__ bias, float* __restrict__ out)
{
    __shared__ unsigned short s_tile[2][64][68];
    __shared__ __align__(16) unsigned char meta_mem[18432];
    float4* mwS = (float4*)meta_mem;
    int4*   moS = (int4*)(meta_mem + 9216);
    float*  out_t = (float*)meta_mem;

    const int t   = threadIdx.x;
    const int bid = blockIdx.x;
    const int b   = bid & 7;
    const int rem = bid >> 3;
    const int ho  = rem >> 1;
    const int wo0 = (rem & 1) << 6;
    const int l   = t & 63;
    const int wv_id = __builtin_amdgcn_readfirstlane(t >> 6);
    const int c0  = wv_id << 4;
    const int cb  = wv_id << 4;

    short8 wtf[2][2];
    #pragma unroll
    for (int kf = 0; kf < 2; ++kf) {
        short8 f;
        int co = cb + (l & 15);
        int cbase = kf * 32 + (l >> 4) * 8;
        #pragma unroll
        for (int e = 0; e < 8; ++e) f[e] = (short)f2bf(wraw[(co * 64 + cbase + e) * 9 + 0]);
        wtf[0][kf] = f;
    }

    for (int i = t; i < 9 * 64; i += 256) {
        int p = i & 63;
        int k = i >> 6;
        int wo = wo0 + p;
        int obase = ((b * 18 + 2 * k) * HH + ho) * WW + wo;
        float oy = off[obase];
        float ox = off[obase + HW];
        float m  = msk[((b * 9 + k) * HH + ho) * WW + wo];
        float py = oy + (float)(k / 3) + (float)(ho - 1);
        float px = ox + (float)(k % 3) + (float)(wo - 1);
        float fy = floorf(py), fx = floorf(px);
        float ly = py - fy,    lx = px - fx;
        int y0 = (int)fy, x0 = (int)fx;
        int y1 = y0 + 1,  x1 = x0 + 1;
        float vy0 = (y0 >= 0 && y0 < HH) ? 1.f : 0.f;
        float vy1 = (y1 >= 0 && y1 < HH) ? 1.f : 0.f;
        float vx0 = (x0 >= 0 && x0 < WW) ? 1.f : 0.f;
        float vx1 = (x1 >= 0 && x1 < WW) ? 1.f : 0.f;
        float w00 = (1.f - ly) * (1.f - lx) * m * vy0 * vx0;
        float w01 = (1.f - ly) * lx         * m * vy0 * vx1;
        float w10 = ly         * (1.f - lx) * m * vy1 * vx0;
        float w11 = ly         * lx         * m * vy1 * vx1;
        int yc0 = min(max(y0, 0), HH - 1), yc1 = min(max(y1, 0), HH - 1);
        int xc0 = min(max(x0, 0), WW - 1), xc1 = min(max(x1, 0), WW - 1);
        mwS[i] = make_float4(w00, w01, w10, w11);
        moS[i] = make_int4(yc0 * WW + xc0, yc0 * WW + xc1,
                           yc1 * WW + xc0, yc1 * WW + xc1);
    }

    const int p = t & 63;
    const float* xb = x + (size_t)(b * 64 + c0) * HW;
    __syncthreads();

    {
        float4 wv = mwS[p];
        int4   ov = moS[p];
        const float* pc = xb;
        #pragma unroll
        for (int i = 0; i < 16; i += 4) {
            float v0 = wv.x * pc[ov.x] + wv.y * pc[ov.y] + wv.z * pc[ov.z] + wv.w * pc[ov.w]; pc += HW;
            float v1 = wv.x * pc[ov.x] + wv.y * pc[ov.y] + wv.z * pc[ov.z] + wv.w * pc[ov.w]; pc += HW;
            float v2 = wv.x * pc[ov.x] + wv.y * pc[ov.y] + wv.z * pc[ov.z] + wv.w * pc[ov.w]; pc += HW;
            float v3 = wv.x * pc[ov.x] + wv.y * pc[ov.y] + wv.z * pc[ov.z] + wv.w * pc[ov.w]; pc += HW;
            uint2 u;
            u.x = (unsigned)f2bf(v0) | ((unsigned)f2bf(v1) << 16);
            u.y = (unsigned)f2bf(v2) | ((unsigned)f2bf(v3) << 16);
            *(uint2*)&s_tile[0][p][c0 + i] = u;
        }
    }
    __syncthreads();

    f32x4 acc[4];
    #pragma unroll
    for (int g = 0; g < 4; ++g) acc[g] = (f32x4){0.f, 0.f, 0.f, 0.f};

    #pragma unroll
    for (int s = 0; s < 9; ++s) {
        if (s < 8) {
            const int kn = s + 1;
            #pragma unroll
            for (int kf = 0; kf < 2; ++kf) {
                short8 f;
                int co = cb + (l & 15);
                int cbase = kf * 32 + (l >> 4) * 8;
                #pragma unroll
                for (int e = 0; e < 8; ++e) f[e] = (short)f2bf(wraw[(co * 64 + cbase + e) * 9 + kn]);
                wtf[kn & 1][kf] = f;
            }
            float4 wv = mwS[kn * 64 + p];
            int4   ov = moS[kn * 64 + p];
            const float* pc = xb;
            #pragma unroll
            for (int i = 0; i < 16; i += 4) {
                float v0 = wv.x * pc[ov.x] + wv.y * pc[ov.y] + wv.z * pc[ov.z] + wv.w * pc[ov.w]; pc += HW;
                float v1 = wv.x * pc[ov.x] + wv.y * pc[ov.y] + wv.z * pc[ov.z] + wv.w * pc[ov.w]; pc += HW;
                float v2 = wv.x * pc[ov.x] + wv.y * pc[ov.y] + wv.z * pc[ov.z] + wv.w * pc[ov.w]; pc += HW;
                float v3 = wv.x * pc[ov.x] + wv.y * pc[ov.y] + wv.z * pc[ov.z] + wv.w * pc[ov.w]; pc += HW;
                uint2 u;
                u.x = (unsigned)f2bf(v0) | ((unsigned)f2bf(v1) << 16);
                u.y = (unsigned)f2bf(v2) | ((unsigned)f2bf(v3) << 16);
                *(uint2*)&s_tile[kn & 1][p][c0 + i] = u;
            }
        }
        #pragma unroll
        for (int g = 0; g < 4; ++g) {
            const int prow = g * 16 + (l & 15);
            const unsigned short* rp = &s_tile[s & 1][prow][(l >> 4) * 8];
            union { short8 v; unsigned long long q[2]; } ua0, ua1;
            ua0.q[0] = *(const unsigned long long*)(rp);
            ua0.q[1] = *(const unsigned long long*)(rp + 4);
            ua1.q[0] = *(const unsigned long long*)(rp + 32);
            ua1.q[1] = *(const unsigned long long*)(rp + 36);
            acc[g] = __builtin_amdgcn_mfma_f32_16x16x32_bf16(ua0.v, wtf[s & 1][0], acc[g], 0, 0, 0);
            acc[g] = __builtin_amdgcn_mfma_f32_16x16x32_bf16(ua1.v, wtf[s & 1][1], acc[g], 0, 0, 0);
        }
        __syncthreads();
    }

    const float bv = bias[cb + (l & 15)];
    #pragma unroll
    for (int g = 0; g < 4; ++g) {
        int co = cb + (l & 15);
        int pxb = g * 16 + (l >> 4) * 4;
        #pragma unroll
        for (int r = 0; r < 4; ++r)
            out_t[co * 68 + pxb + r] = acc[g][r] + bv;
    }
    __syncthreads();
    float* outb = out + (size_t)b * 64 * HW + (size_t)ho * WW + wo0;
    #pragma unroll
    for (int j = 0; j < 4; ++j) {
        int co  = (t >> 4) + j * 16;
        int px0 = (t & 15) << 2;
        float4 v = *(float4*)&out_t[co * 68 + px0];
        *(float4*)&outb[(size_t)co * HW + px0] = v;
    }
}

extern "C" void kernel_launch(void* const* d_in, const int* in_sizes, int n_in,
                              void* d_out, int out_size, void* d_ws, size_t ws_size,
                              hipStream_t stream) {
    const float* x    = (const float*)d_in[0];
    const float* off  = (const float*)d_in[1];
    const float* msk  = (const float*)d_in[2];
    const float* w    = (const float*)d_in[3];
    const float* bias = (const float*)d_in[4];
    float* out = (float*)d_out;

    const size_t need = XT_BYTES + WT_BYTES;
    if (d_ws != nullptr && ws_size >= need) {
        unsigned int*   xt32 = (unsigned int*)d_ws;
        unsigned short* wt   = (unsigned short*)((char*)d_ws + XT_BYTES);
        xtrans_kernel<<<2048, 256, 0, stream>>>(x, xt32);
        wtrans_kernel<<<144, 256, 0, stream>>>(w, wt);
        deform_nhwc<<<2048, 256, 0, stream>>>((const unsigned short*)xt32, off, msk, wt, bias, out);
    } else {
        deform_fallback<<<2048, 256, 0, stream>>>(x, off, msk, w, bias, out);
    }
}

// Round 12
// 47.386 us; speedup vs baseline: 2.0543x; 1.0379x over previous
//
#include <hip/hip_runtime.h>
#include <hip/hip_fp16.h>

#define HH 128
#define WW 128
#define HW (HH*WW)
#define XT_BYTES ((size_t)8 * HW * 64 * 2)   // x_t f16 NHWC
#define WT_BYTES ((size_t)9 * 2 * 4 * 64 * 8 * 2)

typedef __attribute__((ext_vector_type(8))) short short8;
typedef __attribute__((ext_vector_type(4))) float f32x4;
typedef _Float16 half8 __attribute__((ext_vector_type(8)));

static __device__ __forceinline__ unsigned short f2bf(float f) {
    unsigned int u = __float_as_uint(f);
    u += 0x7fffu + ((u >> 16) & 1u);
    return (unsigned short)(u >> 16);
}
static __device__ __forceinline__ unsigned pkrtz(float lo, float hi) {
    auto r = __builtin_amdgcn_cvt_pkrtz(lo, hi);   // __fp16 ext_vector(2)
    return *(unsigned*)&r;
}

// weight (64,64,3,3) fp32 -> f16 B-fragment layout wt[tap][kf][wave][lane][e]
__global__ void wtrans_kernel(const float* __restrict__ w, unsigned short* __restrict__ wt) {
    int i = blockIdx.x * 256 + threadIdx.x;
    if (i < 9 * 2 * 4 * 64 * 8) {
        int e  = i & 7;
        int l  = (i >> 3) & 63;
        int wv = (i >> 9) & 3;
        int kf = (i >> 11) & 1;
        int k  = i >> 12;
        int co = wv * 16 + (l & 15);
        int c  = kf * 32 + (l >> 4) * 8 + e;
        __half hh = __float2half_rn(w[(co * 64 + c) * 9 + k]);
        wt[i] = __half_as_ushort(hh);
    }
}

// x [8,64,128,128] f32 -> x_t [8,HW,64] f16 (NHWC). Block: 64 hw x 64 ch.
__global__ __launch_bounds__(256) void xtrans_kernel(const float* __restrict__ x,
                                                     unsigned int* __restrict__ xt32) {
    __shared__ float tile[64][65];
    const int bid = blockIdx.x;
    const int b   = bid >> 8;
    const int hw0 = (bid & 255) << 6;
    const int t   = threadIdx.x;
    #pragma unroll
    for (int i = 0; i < 16; ++i) {
        int idx = (i << 8) + t;
        int c = idx >> 6, j = idx & 63;
        tile[c][j] = x[(size_t)(((b << 6) + c) << 14) + hw0 + j];
    }
    __syncthreads();
    #pragma unroll
    for (int i = 0; i < 8; ++i) {
        int idx = (i << 8) + t;
        int cp = idx & 31, hw = idx >> 5;
        xt32[((size_t)((b << 14) + hw0 + hw) << 5) + cp] =
            pkrtz(tile[2 * cp][hw], tile[2 * cp + 1][hw]);
    }
}

// Fast path: block = 64 px (half row), 4 waves; wave w: px [16w,16w+16) sampling + couts [16w,16w+16) MFMA.
// r10 structure (best measured). Combine is packed-f16: 4 v_pk_fma_f16-class ops per 2-ch word,
// bilinear weights pre-broadcast as __half2 in LDS (zero unpack/pack VALU).
__global__ __launch_bounds__(256, 4) void deform_nhwc(
    const unsigned short* __restrict__ xt,  // [8][HW][64] f16
    const float* __restrict__ off,
    const float* __restrict__ msk,
    const unsigned short* __restrict__ wt,  // packed f16 B-fragments
    const float* __restrict__ bias,
    float* __restrict__ out)
{
    // [0,16384): two 8 KB sample buffers, XOR-swizzled [64 px][64 ch] f16
    // [16384,25600): moS int4 corner byte-offsets [9*64]
    // [25600,34816): mw4 uint4 = 4x broadcast __half2 bilinear weights [9*64]
    // epilogue: [0,16384) reused as swizzled fp32 out_t
    __shared__ __align__(16) unsigned char smem[34816];
    int4*  moS = (int4*)(smem + 16384);
    uint4* mw4 = (uint4*)(smem + 25600);

    const int t   = threadIdx.x;
    const int bid = blockIdx.x;
    const int b   = bid & 7;            // image <-> XCD affinity
    const int rem = bid >> 3;
    const int ho  = rem >> 1;
    const int wo0 = (rem & 1) << 6;
    const int l   = t & 63;
    const int wv  = __builtin_amdgcn_readfirstlane(t >> 6);

    // ---- per-(tap,pixel) metadata ----
    for (int i = t; i < 9 * 64; i += 256) {
        int p = i & 63;
        int k = i >> 6;
        int wo = wo0 + p;
        int obase = ((b * 18 + 2 * k) * HH + ho) * WW + wo;
        float oy = off[obase];
        float ox = off[obase + HW];
        float m  = msk[((b * 9 + k) * HH + ho) * WW + wo];
        float py = oy + (float)(k / 3) + (float)(ho - 1);
        float px = ox + (float)(k % 3) + (float)(wo - 1);
        float fy = floorf(py), fx = floorf(px);
        float ly = py - fy,    lx = px - fx;
        int y0 = (int)fy, x0 = (int)fx;
        int y1 = y0 + 1,  x1 = x0 + 1;
        float vy0 = (y0 >= 0 && y0 < HH) ? 1.f : 0.f;
        float vy1 = (y1 >= 0 && y1 < HH) ? 1.f : 0.f;
        float vx0 = (x0 >= 0 && x0 < WW) ? 1.f : 0.f;
        float vx1 = (x1 >= 0 && x1 < WW) ? 1.f : 0.f;
        float w00 = (1.f - ly) * (1.f - lx) * m * vy0 * vx0;
        float w01 = (1.f - ly) * lx         * m * vy0 * vx1;
        float w10 = ly         * (1.f - lx) * m * vy1 * vx0;
        float w11 = ly         * lx         * m * vy1 * vx1;
        int yc0 = min(max(y0, 0), HH - 1), yc1 = min(max(y1, 0), HH - 1);
        int xc0 = min(max(x0, 0), WW - 1), xc1 = min(max(x1, 0), WW - 1);
        moS[i] = make_int4((yc0 * WW + xc0) << 7, (yc0 * WW + xc1) << 7,
                           (yc1 * WW + xc0) << 7, (yc1 * WW + xc1) << 7);
        __half2 W00 = __half2half2(__float2half_rn(w00));
        __half2 W01 = __half2half2(__float2half_rn(w01));
        __half2 W10 = __half2half2(__float2half_rn(w10));
        __half2 W11 = __half2half2(__float2half_rn(w11));
        mw4[i] = make_uint4(*(unsigned*)&W00, *(unsigned*)&W01,
                            *(unsigned*)&W10, *(unsigned*)&W11);
    }

    const char* ib   = (const char*)xt + (size_t)b * HW * 128;  // image base (bytes)
    const int  chb   = (l & 7) << 4;               // byte offset of this lane's 8 channels
    const int  px0_  = (wv << 4) + (l >> 3);       // r=0 pixel
    int st_woff[2];
    st_woff[0] = px0_ * 128 + (chb ^ ((px0_ & 7) << 4));
    st_woff[1] = st_woff[0] + 8 * 128;             // (px0_+8)&7 == px0_&7
    const int lq = (l >> 4) << 4;                  // fragment col-byte base
    const int sw = (l & 7) << 4;                   // read-side swizzle (prow&7 == l&7)

    uint4 g0[4], g1[4];    // in-flight gathers: [corner] for r=0 / r=1 pixels
    half8 wtf[2][2];       // rotating B-fragments

    #define ISSUE_TAP(kk) {                                          \
        int4 ob0 = moS[(kk) * 64 + px0_];                            \
        g0[0] = *(const uint4*)(ib + ob0.x + chb);                   \
        g0[1] = *(const uint4*)(ib + ob0.y + chb);                   \
        g0[2] = *(const uint4*)(ib + ob0.z + chb);                   \
        g0[3] = *(const uint4*)(ib + ob0.w + chb);                   \
        int4 ob1 = moS[(kk) * 64 + px0_ + 8];                        \
        g1[0] = *(const uint4*)(ib + ob1.x + chb);                   \
        g1[1] = *(const uint4*)(ib + ob1.y + chb);                   \
        g1[2] = *(const uint4*)(ib + ob1.z + chb);                   \
        g1[3] = *(const uint4*)(ib + ob1.w + chb);                   \
    }

    // packed-f16 combine: one 2-ch word = 3 hfma2 + 1 hmul2
    #define CMBH(dst_, c00, c01, c10, c11) {                         \
        __half2 a_ = __hmul2(*(__half2*)&(c11), W11);                \
        a_ = __hfma2(*(__half2*)&(c10), W10, a_);                    \
        a_ = __hfma2(*(__half2*)&(c01), W01, a_);                    \
        a_ = __hfma2(*(__half2*)&(c00), W00, a_);                    \
        dst_ = *(unsigned*)&a_;                                      \
    }

    #define COMBINE_STORE(kk, dstb) {                                \
        {                                                            \
            uint4 wp = mw4[(kk) * 64 + px0_];                        \
            __half2 W00 = *(__half2*)&wp.x, W01 = *(__half2*)&wp.y;  \
            __half2 W10 = *(__half2*)&wp.z, W11 = *(__half2*)&wp.w;  \
            uint4 uv;                                                \
            CMBH(uv.x, g0[0].x, g0[1].x, g0[2].x, g0[3].x)           \
            CMBH(uv.y, g0[0].y, g0[1].y, g0[2].y, g0[3].y)           \
            CMBH(uv.z, g0[0].z, g0[1].z, g0[2].z, g0[3].z)           \
            CMBH(uv.w, g0[0].w, g0[1].w, g0[2].w, g0[3].w)           \
            *(uint4*)((dstb) + st_woff[0]) = uv;                     \
        }                                                            \
        {                                                            \
            uint4 wp = mw4[(kk) * 64 + px0_ + 8];                    \
            __half2 W00 = *(__half2*)&wp.x, W01 = *(__half2*)&wp.y;  \
            __half2 W10 = *(__half2*)&wp.z, W11 = *(__half2*)&wp.w;  \
            uint4 uv;                                                \
            CMBH(uv.x, g1[0].x, g1[1].x, g1[2].x, g1[3].x)           \
            CMBH(uv.y, g1[0].y, g1[1].y, g1[2].y, g1[3].y)           \
            CMBH(uv.z, g1[0].z, g1[1].z, g1[2].z, g1[3].z)           \
            CMBH(uv.w, g1[0].w, g1[1].w, g1[2].w, g1[3].w)           \
            *(uint4*)((dstb) + st_woff[1]) = uv;                     \
        }                                                            \
    }

    __syncthreads();   // meta visible

    // ---- prologue: tap 0 (no MFMA to hide under) ----
    ISSUE_TAP(0)
    #pragma unroll
    for (int kf = 0; kf < 2; ++kf) {
        short8 s = *(const short8*)(wt + (((kf * 4 + wv) * 64 + l) << 3));
        wtf[0][kf] = *(half8*)&s;
    }
    COMBINE_STORE(0, smem)
    __syncthreads();

    f32x4 acc[4];
    #pragma unroll
    for (int g = 0; g < 4; ++g) acc[g] = (f32x4){0.f, 0.f, 0.f, 0.f};

    // ---- 9 stages: issue(k+1) / MFMA(k) / combine(k+1), 1 sync each ----
    #pragma unroll
    for (int s = 0; s < 9; ++s) {
        if (s < 8) {
            const int kn = s + 1;
            ISSUE_TAP(kn)
            #pragma unroll
            for (int kf = 0; kf < 2; ++kf) {
                short8 sv = *(const short8*)(wt + ((((kn * 2 + kf) * 4 + wv) * 64 + l) << 3));
                wtf[kn & 1][kf] = *(half8*)&sv;
            }
        }
        __builtin_amdgcn_sched_barrier(0);   // loads stay above (issued early)
        {
            const unsigned char* rb = smem + ((s & 1) << 13);
            #pragma unroll
            for (int g = 0; g < 4; ++g) {
                const int prow = g * 16 + (l & 15);
                short8 a0 = *(const short8*)(rb + prow * 128 + (lq ^ sw));
                short8 a1 = *(const short8*)(rb + prow * 128 + ((64 + lq) ^ sw));
                acc[g] = __builtin_amdgcn_mfma_f32_16x16x32_f16(*(half8*)&a0, wtf[s & 1][0], acc[g], 0, 0, 0);
                acc[g] = __builtin_amdgcn_mfma_f32_16x16x32_f16(*(half8*)&a1, wtf[s & 1][1], acc[g], 0, 0, 0);
            }
        }
        __builtin_amdgcn_sched_barrier(0);   // vmcnt drain lands after the MFMAs
        if (s < 8) {
            COMBINE_STORE(s + 1, smem + (((s + 1) & 1) << 13))
        }
        __syncthreads();
    }
    #undef ISSUE_TAP
    #undef CMBH
    #undef COMBINE_STORE

    // ---- epilogue: swizzled transpose through LDS, coalesced float4 stores ----
    float* out_t = (float*)smem;   // [64 co][256 B rows], XOR-swizzled
    const int cb = wv << 4;
    const int co_e = cb + (l & 15);
    const float bv = bias[co_e];
    const int swE = (co_e & 15) << 4;
    #pragma unroll
    for (int g = 0; g < 4; ++g) {
        int pxb = (g << 6) + ((l >> 4) << 4);   // byte col of pixel group
        float4 v = make_float4(acc[g][0] + bv, acc[g][1] + bv, acc[g][2] + bv, acc[g][3] + bv);
        *(float4*)((unsigned char*)out_t + co_e * 256 + (pxb ^ swE)) = v;
    }
    __syncthreads();
    float* outb = out + (size_t)b * 64 * HW + (size_t)ho * WW + wo0;
    #pragma unroll
    for (int j = 0; j < 4; ++j) {
        int co   = (t >> 4) + (j << 4);
        int colb = (t & 15) << 4;
        float4 v = *(const float4*)((const unsigned char*)out_t + co * 256 + (colb ^ ((co & 15) << 4)));
        *(float4*)&outb[(size_t)co * HW + ((t & 15) << 2)] = v;
    }
}

// -------- fallback (NCHW gather, raw weights, bf16 MFMA) for tiny workspace --------
__global__ __launch_bounds__(256, 4) void deform_fallback(
    const float* __restrict__ x, const float* __restrict__ off,
    const float* __restrict__ msk, const float* __restrict__ wraw,
    const float* __restrict__ bias, float* __restrict__ out)
{
    __shared__ unsigned short s_tile[2][64][68];
    __shared__ __align__(16) unsigned char meta_mem[18432];
    float4* mwS = (float4*)meta_mem;
    int4*   moS = (int4*)(meta_mem + 9216);
    float*  out_t = (float*)meta_mem;

    const int t   = threadIdx.x;
    const int bid = blockIdx.x;
    const int b   = bid & 7;
    const int rem = bid >> 3;
    const int ho  = rem >> 1;
    const int wo0 = (rem & 1) << 6;
    const int l   = t & 63;
    const int wv_id = __builtin_amdgcn_readfirstlane(t >> 6);
    const int c0  = wv_id << 4;
    const int cb  = wv_id << 4;

    short8 wtf[2][2];
    #pragma unroll
    for (int kf = 0; kf < 2; ++kf) {
        short8 f;
        int co = cb + (l & 15);
        int cbase = kf * 32 + (l >> 4) * 8;
        #pragma unroll
        for (int e = 0; e < 8; ++e) f[e] = (short)f2bf(wraw[(co * 64 + cbase + e) * 9 + 0]);
        wtf[0][kf] = f;
    }

    for (int i = t; i < 9 * 64; i += 256) {
        int p = i & 63;
        int k = i >> 6;
        int wo = wo0 + p;
        int obase = ((b * 18 + 2 * k) * HH + ho) * WW + wo;
        float oy = off[obase];
        float ox = off[obase + HW];
        float m  = msk[((b * 9 + k) * HH + ho) * WW + wo];
        float py = oy + (float)(k / 3) + (float)(ho - 1);
        float px = ox + (float)(k % 3) + (float)(wo - 1);
        float fy = floorf(py), fx = floorf(px);
        float ly = py - fy,    lx = px - fx;
        int y0 = (int)fy, x0 = (int)fx;
        int y1 = y0 + 1,  x1 = x0 + 1;
        float vy0 = (y0 >= 0 && y0 < HH) ? 1.f : 0.f;
        float vy1 = (y1 >= 0 && y1 < HH) ? 1.f : 0.f;
        float vx0 = (x0 >= 0 && x0 < WW) ? 1.f : 0.f;
        float vx1 = (x1 >= 0 && x1 < WW) ? 1.f : 0.f;
        float w00 = (1.f - ly) * (1.f - lx) * m * vy0 * vx0;
        float w01 = (1.f - ly) * lx         * m * vy0 * vx1;
        float w10 = ly         * (1.f - lx) * m * vy1 * vx0;
        float w11 = ly         * lx         * m * vy1 * vx1;
        int yc0 = min(max(y0, 0), HH - 1), yc1 = min(max(y1, 0), HH - 1);
        int xc0 = min(max(x0, 0), WW - 1), xc1 = min(max(x1, 0), WW - 1);
        mwS[i] = make_float4(w00, w01, w10, w11);
        moS[i] = make_int4(yc0 * WW + xc0, yc0 * WW + xc1,
                           yc1 * WW + xc0, yc1 * WW + xc1);
    }

    const int p = t & 63;
    const float* xb = x + (size_t)(b * 64 + c0) * HW;
    __syncthreads();

    {
        float4 wv = mwS[p];
        int4   ov = moS[p];
        const float* pc = xb;
        #pragma unroll
        for (int i = 0; i < 16; i += 4) {
            float v0 = wv.x * pc[ov.x] + wv.y * pc[ov.y] + wv.z * pc[ov.z] + wv.w * pc[ov.w]; pc += HW;
            float v1 = wv.x * pc[ov.x] + wv.y * pc[ov.y] + wv.z * pc[ov.z] + wv.w * pc[ov.w]; pc += HW;
            float v2 = wv.x * pc[ov.x] + wv.y * pc[ov.y] + wv.z * pc[ov.z] + wv.w * pc[ov.w]; pc += HW;
            float v3 = wv.x * pc[ov.x] + wv.y * pc[ov.y] + wv.z * pc[ov.z] + wv.w * pc[ov.w]; pc += HW;
            uint2 u;
            u.x = (unsigned)f2bf(v0) | ((unsigned)f2bf(v1) << 16);
            u.y = (unsigned)f2bf(v2) | ((unsigned)f2bf(v3) << 16);
            *(uint2*)&s_tile[0][p][c0 + i] = u;
        }
    }
    __syncthreads();

    f32x4 acc[4];
    #pragma unroll
    for (int g = 0; g < 4; ++g) acc[g] = (f32x4){0.f, 0.f, 0.f, 0.f};

    #pragma unroll
    for (int s = 0; s < 9; ++s) {
        if (s < 8) {
            const int kn = s + 1;
            #pragma unroll
            for (int kf = 0; kf < 2; ++kf) {
                short8 f;
                int co = cb + (l & 15);
                int cbase = kf * 32 + (l >> 4) * 8;
                #pragma unroll
                for (int e = 0; e < 8; ++e) f[e] = (short)f2bf(wraw[(co * 64 + cbase + e) * 9 + kn]);
                wtf[kn & 1][kf] = f;
            }
            float4 wv = mwS[kn * 64 + p];
            int4   ov = moS[kn * 64 + p];
            const float* pc = xb;
            #pragma unroll
            for (int i = 0; i < 16; i += 4) {
                float v0 = wv.x * pc[ov.x] + wv.y * pc[ov.y] + wv.z * pc[ov.z] + wv.w * pc[ov.w]; pc += HW;
                float v1 = wv.x * pc[ov.x] + wv.y * pc[ov.y] + wv.z * pc[ov.z] + wv.w * pc[ov.w]; pc += HW;
                float v2 = wv.x * pc[ov.x] + wv.y * pc[ov.y] + wv.z * pc[ov.z] + wv.w * pc[ov.w]; pc += HW;
                float v3 = wv.x * pc[ov.x] + wv.y * pc[ov.y] + wv.z * pc[ov.z] + wv.w * pc[ov.w]; pc += HW;
                uint2 u;
                u.x = (unsigned)f2bf(v0) | ((unsigned)f2bf(v1) << 16);
                u.y = (unsigned)f2bf(v2) | ((unsigned)f2bf(v3) << 16);
                *(uint2*)&s_tile[kn & 1][p][c0 + i] = u;
            }
        }
        #pragma unroll
        for (int g = 0; g < 4; ++g) {
            const int prow = g * 16 + (l & 15);
            const unsigned short* rp = &s_tile[s & 1][prow][(l >> 4) * 8];
            union { short8 v; unsigned long long q[2]; } ua0, ua1;
            ua0.q[0] = *(const unsigned long long*)(rp);
            ua0.q[1] = *(const unsigned long long*)(rp + 4);
            ua1.q[0] = *(const unsigned long long*)(rp + 32);
            ua1.q[1] = *(const unsigned long long*)(rp + 36);
            acc[g] = __builtin_amdgcn_mfma_f32_16x16x32_bf16(ua0.v, wtf[s & 1][0], acc[g], 0, 0, 0);
            acc[g] = __builtin_amdgcn_mfma_f32_16x16x32_bf16(ua1.v, wtf[s & 1][1], acc[g], 0, 0, 0);
        }
        __syncthreads();
    }

    const float bv = bias[cb + (l & 15)];
    #pragma unroll
    for (int g = 0; g < 4; ++g) {
        int co = cb + (l & 15);
        int pxb = g * 16 + (l >> 4) * 4;
        #pragma unroll
        for (int r = 0; r < 4; ++r)
            out_t[co * 68 + pxb + r] = acc[g][r] + bv;
    }
    __syncthreads();
    float* outb = out + (size_t)b * 64 * HW + (size_t)ho * WW + wo0;
    #pragma unroll
    for (int j = 0; j < 4; ++j) {
        int co  = (t >> 4) + j * 16;
        int px0 = (t & 15) << 2;
        float4 v = *(float4*)&out_t[co * 68 + px0];
        *(float4*)&outb[(size_t)co * HW + px0] = v;
    }
}

extern "C" void kernel_launch(void* const* d_in, const int* in_sizes, int n_in,
                              void* d_out, int out_size, void* d_ws, size_t ws_size,
                              hipStream_t stream) {
    const float* x    = (const float*)d_in[0];
    const float* off  = (const float*)d_in[1];
    const float* msk  = (const float*)d_in[2];
    const float* w    = (const float*)d_in[3];
    const float* bias = (const float*)d_in[4];
    float* out = (float*)d_out;

    const size_t need = XT_BYTES + WT_BYTES;
    if (d_ws != nullptr && ws_size >= need) {
        unsigned int*   xt32 = (unsigned int*)d_ws;
        unsigned short* wt   = (unsigned short*)((char*)d_ws + XT_BYTES);
        xtrans_kernel<<<2048, 256, 0, stream>>>(x, xt32);
        wtrans_kernel<<<144, 256, 0, stream>>>(w, wt);
        deform_nhwc<<<2048, 256, 0, stream>>>((const unsigned short*)xt32, off, msk, wt, bias, out);
    } else {
        deform_fallback<<<2048, 256, 0, stream>>>(x, off, msk, w, bias, out);
    }
}